// Round 14
// baseline (11350.240 us; speedup 1.0000x reference)
//
#include <hip/hip_runtime.h>
#include <math.h>

#define B_ 512
#define T_ 49
#define D_ 256
#define M_ 1024
#define L_ 4
#define OUT_ 151
#define BT_ 25088            // B_*T_
#define NTOK5 (5*BT_)
#define THRESH 0.02f

typedef __bf16 bf16x8 __attribute__((ext_vector_type(8)));
typedef float f32x4 __attribute__((ext_vector_type(4)));
typedef unsigned short us;

__device__ __forceinline__ float gelu_t(float x){
    float u = 0.7978845608028654f * x * (1.0f + 0.044715f*x*x);
    float e = __expf(-2.0f*u);
    return __fdividef(x, 1.0f + e);
}
__device__ __forceinline__ us f2bf(float f){
    unsigned int u = __float_as_uint(f);
    u += 0x7fffu + ((u>>16)&1u);          // RNE
    return (us)(u>>16);
}
__device__ __forceinline__ float bf2f(us h){
    return __uint_as_float(((unsigned int)h)<<16);
}
__device__ __forceinline__ void gload16(const void* g, void* l){
    __builtin_amdgcn_global_load_lds(
        (const __attribute__((address_space(1))) void*)g,
        (__attribute__((address_space(3))) void*)l, 16, 0, 0);
}

// ---------------- copy 5 input streams into contiguous X buffer ----------------
__global__ void copy_in_kernel(const float* __restrict__ a0, const float* __restrict__ a1,
                               const float* __restrict__ a2, const float* __restrict__ a3,
                               const float* __restrict__ a4, float* __restrict__ dst){
    size_t i = (size_t)blockIdx.x*256 + threadIdx.x;
    if (i >= (size_t)NTOK5*64) return;
    int slot = (int)(i / ((size_t)BT_*64));
    size_t off = i % ((size_t)BT_*64);
    const float* src = slot==0?a0: slot==1?a1: slot==2?a2: slot==3?a3: a4;
    ((float4*)dst)[i] = ((const float4*)src)[off];
}

// ---------------- double bias (for linear-merged P3) ----------------
__global__ void dblb_kernel(const float* __restrict__ b, float* __restrict__ o, int n){
    int i = blockIdx.x*256 + threadIdx.x;
    if (i < n) o[i] = 2.0f*b[i];
}

// ---------------- generic LayerNorm D=256; OBF: bf16 or fp32 out ----------------
template<bool OBF>
__global__ void ln_kernel(const float* __restrict__ x, const float* __restrict__ g,
                          const float* __restrict__ b, void* __restrict__ y, int nrows){
    int row = blockIdx.x*4 + (threadIdx.x>>6);
    if (row >= nrows) return;
    int lane = threadIdx.x & 63;
    float4 v = ((const float4*)(x + (size_t)row*D_))[lane];
    float s  = v.x+v.y+v.z+v.w;
    float sq = v.x*v.x + v.y*v.y + v.z*v.z + v.w*v.w;
    #pragma unroll
    for (int o=32;o;o>>=1){ s += __shfl_xor(s,o,64); sq += __shfl_xor(sq,o,64); }
    float mu = s*(1.0f/256.0f);
    float rstd = rsqrtf(sq*(1.0f/256.0f) - mu*mu + 1e-5f);
    float4 gv = ((const float4*)g)[lane];
    float4 bv = ((const float4*)b)[lane];
    float o0 = (v.x-mu)*rstd*gv.x + bv.x;
    float o1 = (v.y-mu)*rstd*gv.y + bv.y;
    float o2 = (v.z-mu)*rstd*gv.z + bv.z;
    float o3 = (v.w-mu)*rstd*gv.w + bv.w;
    if (OBF){
        ushort4 o4; o4.x=f2bf(o0); o4.y=f2bf(o1); o4.z=f2bf(o2); o4.w=f2bf(o3);
        ((ushort4*)((us*)y + (size_t)row*D_))[lane] = o4;
    } else {
        float4 o4; o4.x=o0; o4.y=o1; o4.z=o2; o4.w=o3;
        ((float4*)((float*)y + (size_t)row*D_))[lane] = o4;
    }
}

// ---------------- encoder LayerNorm over ALL 5BT rows: params by stream group ----------------
__global__ void ln_enc_kernel(const float* __restrict__ x,
                              const float* __restrict__ g0, const float* __restrict__ b0,
                              const float* __restrict__ g1, const float* __restrict__ b1,
                              us* __restrict__ y){
    int row = blockIdx.x*4 + (threadIdx.x>>6);
    if (row >= NTOK5) return;
    int lane = threadIdx.x & 63;
    const float* g = (row < 2*BT_) ? g0 : g1;
    const float* b = (row < 2*BT_) ? b0 : b1;
    float4 v = ((const float4*)(x + (size_t)row*D_))[lane];
    float s  = v.x+v.y+v.z+v.w;
    float sq = v.x*v.x + v.y*v.y + v.z*v.z + v.w*v.w;
    #pragma unroll
    for (int o=32;o;o>>=1){ s += __shfl_xor(s,o,64); sq += __shfl_xor(sq,o,64); }
    float mu = s*(1.0f/256.0f);
    float rstd = rsqrtf(sq*(1.0f/256.0f) - mu*mu + 1e-5f);
    float4 gv = ((const float4*)g)[lane];
    float4 bv = ((const float4*)b)[lane];
    ushort4 o4;
    o4.x = f2bf((v.x-mu)*rstd*gv.x + bv.x);
    o4.y = f2bf((v.y-mu)*rstd*gv.y + bv.y);
    o4.z = f2bf((v.z-mu)*rstd*gv.z + bv.z);
    o4.w = f2bf((v.w-mu)*rstd*gv.w + bv.w);
    ((ushort4*)(y + (size_t)row*D_))[lane] = o4;
}

// ---------------- weight transpose+convert: W[g][K][N] fp32 -> Wt[g][N][K] bf16 ----------------
__global__ void wtrans_kernel(const float* __restrict__ W, us* __restrict__ Wt,
                              int K, int N){
    int g = blockIdx.z;
    __shared__ float t[32][33];
    int k0 = blockIdx.y*32, n0 = blockIdx.x*32;
    int tx = threadIdx.x&31, ty = threadIdx.x>>5;
    for (int r=ty; r<32; r+=8){
        int k = k0+r, n = n0+tx;
        t[r][tx] = (k<K && n<N) ? W[(size_t)g*K*N + (size_t)k*N + n] : 0.f;
    }
    __syncthreads();
    for (int r=ty; r<32; r+=8){
        int n = n0+r, k = k0+tx;
        if (n<N && k<K) Wt[(size_t)g*N*K + (size_t)n*K + k] = f2bf(t[tx][r]);
    }
}

__device__ __forceinline__ void gemm_compute(const us* As, const us* Bs,
        int wr, int wc, int lr, int kg, f32x4 (&acc)[4][4]){
    bf16x8 av[4], bv[4];
    #pragma unroll
    for (int mi=0;mi<4;mi++){
        int r = wr*64 + mi*16 + lr;
        av[mi] = *(const bf16x8*)(&As[r*32 + ((kg ^ ((r>>1)&3))<<3)]);
    }
    #pragma unroll
    for (int ni=0;ni<4;ni++){
        int c = wc*64 + ni*16 + lr;
        bv[ni] = *(const bf16x8*)(&Bs[c*32 + ((kg ^ ((c>>1)&3))<<3)]);
    }
    #pragma unroll
    for (int mi=0;mi<4;mi++)
        #pragma unroll
        for (int ni=0;ni<4;ni++)
            acc[mi][ni] = __builtin_amdgcn_mfma_f32_16x16x32_bf16(av[mi], bv[ni], acc[mi][ni], 0, 0, 0);
}

// ---------------- bf16 MFMA GEMM, 2-buf counted-vmcnt pipeline + XCD swizzle ----------------
// 128x128 tile, BK=32, 4 waves. RIN: 0 none, 1 fp32 resid, 2 bf16 resid (post-ACT).
// OBF && RIN==0: single-round bf16 LDS epilogue (1 barrier, punit swizzle);
// otherwise the proven 2-round fp32 epilogue.
template<int ACT, int RIN, bool OBF>
__global__ __launch_bounds__(256) void mfma_gemm(
    const us* __restrict__ A, const us* __restrict__ Wt,
    const float* __restrict__ bias, const void* __restrict__ resid,
    void* __restrict__ Cout, int Mr, int N, int K)
{
    __shared__ __align__(16) us SM[2*8192];            // 2 bufs x (A 8KB + B 8KB)
    const int nwg  = gridDim.x*gridDim.y;
    const int flat = blockIdx.y*gridDim.x + blockIdx.x;
    const int qq = nwg>>3, rr = nwg&7;
    const int xcd = flat&7, sidx = flat>>3;
    const int logical = (xcd<rr) ? (xcd*(qq+1)+sidx) : (rr*(qq+1)+(xcd-rr)*qq+sidx);
    const int bn = (logical % gridDim.x)*128;
    const int bm = (logical / gridDim.x)*128;
    const int tid = threadIdx.x;
    const int lane = tid&63, w = tid>>6;
    const int wr = w>>1, wc = w&1;
    const int lr = lane&15, kg = lane>>4;
    f32x4 acc[4][4] = {};

    const int j0 = tid, j1 = tid+256;
    const int row0 = j0>>2, row1 = j1>>2;
    const int k8s0 = (j0&3) ^ ((row0>>1)&3);
    const int k8s1 = (j1&3) ^ ((row1>>1)&3);
    int ga0 = bm+row0; if (ga0>=Mr) ga0=Mr-1;
    int ga1 = bm+row1; if (ga1>=Mr) ga1=Mr-1;
    int gb0 = bn+row0; if (gb0>=N) gb0=N-1;
    int gb1 = bn+row1; if (gb1>=N) gb1=N-1;
    const us* a0p = A  + (size_t)ga0*K + k8s0*8;
    const us* a1p = A  + (size_t)ga1*K + k8s1*8;
    const us* b0p = Wt + (size_t)gb0*K + k8s0*8;
    const us* b1p = Wt + (size_t)gb1*K + k8s1*8;

    const int nk = K >> 5;
    {
        us* b0 = SM;
        gload16(a0p, b0 + j0*8);
        gload16(a1p, b0 + j1*8);
        gload16(b0p, b0 + 4096 + j0*8);
        gload16(b1p, b0 + 4096 + j1*8);
        us* b1 = SM + 8192;
        gload16(a0p+32, b1 + j0*8);
        gload16(a1p+32, b1 + j1*8);
        gload16(b0p+32, b1 + 4096 + j0*8);
        gload16(b1p+32, b1 + 4096 + j1*8);
    }
    int cur = 0;
    for (int t=0; t<nk-1; ++t){
        asm volatile("s_waitcnt vmcnt(4)" ::: "memory");
        __builtin_amdgcn_s_barrier();
        __builtin_amdgcn_sched_barrier(0);
        const us* cbase = SM + cur*8192;
        gemm_compute(cbase, cbase+4096, wr, wc, lr, kg, acc);
        __builtin_amdgcn_sched_barrier(0);
        __builtin_amdgcn_s_barrier();
        if (t+2 < nk){
            us* nbase = SM + cur*8192;
            int k0 = (t+2)<<5;
            gload16(a0p+k0, nbase + j0*8);
            gload16(a1p+k0, nbase + j1*8);
            gload16(b0p+k0, nbase + 4096 + j0*8);
            gload16(b1p+k0, nbase + 4096 + j1*8);
        }
        cur ^= 1;
    }
    asm volatile("s_waitcnt vmcnt(0)" ::: "memory");
    __builtin_amdgcn_s_barrier();
    __builtin_amdgcn_sched_barrier(0);
    {
        const us* cbase = SM + cur*8192;
        gemm_compute(cbase, cbase+4096, wr, wc, lr, kg, acc);
    }
    __syncthreads();

    if (OBF && RIN==0){
        // ---- single-round bf16 epilogue: 128x128 us = 32KB, 1 barrier ----
        // punit = unit ^ h(row), h = ((row>>2)&3)|((row&1)<<2):
        //  write: 8 punits x 4 bank-offsets = 32 banks, 2 lanes each (free)
        //  read:  rows 16 apart share h -> 2-way (free); stores 8rows x 128B coalesced
        us* Cs16 = (us*)SM;
        #pragma unroll
        for (int mi=0;mi<4;mi++){
            #pragma unroll
            for (int ni=0;ni<4;ni++){
                #pragma unroll
                for (int r4=0;r4<4;r4++){
                    int row = wr*64 + mi*16 + kg*4 + r4;
                    int col = wc*64 + ni*16 + lr;
                    float v = acc[mi][ni][r4];
                    if (bias) v += bias[bn + col];
                    if (ACT==1) v = gelu_t(v);
                    int h = ((row>>2)&3) | ((row&1)<<2);
                    int punit = (col>>3) ^ h;
                    Cs16[row*128 + punit*8 + (col&7)] = f2bf(v);
                }
            }
        }
        __syncthreads();
        {
            int rbase = tid>>3, seg = tid&7;
            #pragma unroll
            for (int pass=0; pass<8; ++pass){
                int row = rbase + (pass>>1)*32;
                int half = pass&1;
                int grow = bm + row;
                if (grow < Mr){
                    int h = ((row>>2)&3) | ((row&1)<<2);
                    int punit = (half*8+seg) ^ h;
                    *(uint4*)((us*)Cout + (size_t)grow*N + bn + half*64 + seg*8)
                        = *(const uint4*)&Cs16[row*128 + punit*8];
                }
            }
        }
        return;
    }

    // ---- 2-round fp32 epilogue (RIN paths / fp32 out) ----
    float* Cs = (float*)SM;      // 64 x 128 f32 = 32KB
    #pragma unroll
    for (int er=0; er<2; er++){
        #pragma unroll
        for (int ml=0; ml<2; ml++){
            int mi = er*2 + ml;
            #pragma unroll
            for (int ni=0;ni<4;ni++){
                #pragma unroll
                for (int r4=0;r4<4;r4++){
                    int lrow = wr*32 + ml*16 + kg*4 + r4;
                    int lcol = wc*64 + ni*16 + lr;
                    int pcol = lcol ^ (((lrow>>2)&1)<<4);
                    float v = acc[mi][ni][r4];
                    if (bias) v += bias[bn + lcol];
                    if (ACT==1) v = gelu_t(v);
                    Cs[lrow*128 + pcol] = v;
                }
            }
        }
        __syncthreads();
        #pragma unroll
        for (int s=0; s<2; s++){
            int lrow = (tid>>3) + s*32;
            int tseg = tid&7;
            int pseg = tseg ^ ((lrow>>2)&1);
            const float4* src = (const float4*)&Cs[lrow*128 + pseg*16];
            float4 v0=src[0], v1=src[1], v2=src[2], v3=src[3];
            int grow = bm + (lrow>>5)*64 + (er*2 + ((lrow>>4)&1))*16 + (lrow&15);
            int gcol = bn + tseg*16;
            if (grow < Mr){
                if (RIN==1){
                    const float4* rp = (const float4*)((const float*)resid + (size_t)grow*N + gcol);
                    float4 r0=rp[0], r1=rp[1], r2=rp[2], r3=rp[3];
                    v0.x+=r0.x; v0.y+=r0.y; v0.z+=r0.z; v0.w+=r0.w;
                    v1.x+=r1.x; v1.y+=r1.y; v1.z+=r1.z; v1.w+=r1.w;
                    v2.x+=r2.x; v2.y+=r2.y; v2.z+=r2.z; v2.w+=r2.w;
                    v3.x+=r3.x; v3.y+=r3.y; v3.z+=r3.z; v3.w+=r3.w;
                } else if (RIN==2){
                    const uint4* rp = (const uint4*)((const us*)resid + (size_t)grow*N + gcol);
                    uint4 u0=rp[0], u1=rp[1];
                    v0.x+=bf2f((us)(u0.x&0xffff)); v0.y+=bf2f((us)(u0.x>>16));
                    v0.z+=bf2f((us)(u0.y&0xffff)); v0.w+=bf2f((us)(u0.y>>16));
                    v1.x+=bf2f((us)(u0.z&0xffff)); v1.y+=bf2f((us)(u0.z>>16));
                    v1.z+=bf2f((us)(u0.w&0xffff)); v1.w+=bf2f((us)(u0.w>>16));
                    v2.x+=bf2f((us)(u1.x&0xffff)); v2.y+=bf2f((us)(u1.x>>16));
                    v2.z+=bf2f((us)(u1.y&0xffff)); v2.w+=bf2f((us)(u1.y>>16));
                    v3.x+=bf2f((us)(u1.z&0xffff)); v3.y+=bf2f((us)(u1.z>>16));
                    v3.z+=bf2f((us)(u1.w&0xffff)); v3.w+=bf2f((us)(u1.w>>16));
                }
                if (OBF){
                    unsigned int w0 = (unsigned)f2bf(v0.x) | ((unsigned)f2bf(v0.y)<<16);
                    unsigned int w1 = (unsigned)f2bf(v0.z) | ((unsigned)f2bf(v0.w)<<16);
                    unsigned int w2 = (unsigned)f2bf(v1.x) | ((unsigned)f2bf(v1.y)<<16);
                    unsigned int w3 = (unsigned)f2bf(v1.z) | ((unsigned)f2bf(v1.w)<<16);
                    unsigned int w4 = (unsigned)f2bf(v2.x) | ((unsigned)f2bf(v2.y)<<16);
                    unsigned int w5 = (unsigned)f2bf(v2.z) | ((unsigned)f2bf(v2.w)<<16);
                    unsigned int w6 = (unsigned)f2bf(v3.x) | ((unsigned)f2bf(v3.y)<<16);
                    unsigned int w7 = (unsigned)f2bf(v3.z) | ((unsigned)f2bf(v3.w)<<16);
                    uint4* op = (uint4*)((us*)Cout + (size_t)grow*N + gcol);
                    uint4 u0; u0.x=w0; u0.y=w1; u0.z=w2; u0.w=w3;
                    uint4 u1; u1.x=w4; u1.y=w5; u1.z=w6; u1.w=w7;
                    op[0]=u0; op[1]=u1;
                } else {
                    float4* op = (float4*)((float*)Cout + (size_t)grow*N + gcol);
                    op[0]=v0; op[1]=v1; op[2]=v2; op[3]=v3;
                }
            }
        }
        __syncthreads();
    }
}

// ---------------- fp32 tiled GEMM (head only) ----------------
#define GBK 16
template<int ACT, bool RES>
__global__ void gemm_kernel(const float* __restrict__ A, const float* __restrict__ W,
                            const float* __restrict__ bias, const float* __restrict__ resid,
                            float* __restrict__ C, int N, int K, int KB){
    __shared__ float As[GBK][68];
    __shared__ float Ws[GBK][68];
    const int bm = blockIdx.y*64;
    const int bn = blockIdx.x*64;
    const int tid = threadIdx.x;
    const int tr = tid>>4, tc = tid&15;
    float acc[4][4] = {{0.f}};
    for (int k0 = 0; k0 < K; k0 += GBK){
        {
            int r = tid>>2;
            int c = (tid&3)<<2;
            int row = bm + r;
            float4 v = make_float4(0.f,0.f,0.f,0.f);
            if (row < N) v = *(const float4*)(A + (size_t)row*K + k0 + c);
            As[c+0][r]=v.x; As[c+1][r]=v.y; As[c+2][r]=v.z; As[c+3][r]=v.w;
        }
        {
            int r = tid>>4;
            int c = (tid&15)<<2;
            int col = bn + c;
            const float* wp = W + (size_t)(k0+r)*KB + col;
            float4 v;
            if ((KB & 3) == 0 && col + 3 < KB){
                v = *(const float4*)wp;
            } else {
                v.x = (col+0<KB)? wp[0]:0.f;
                v.y = (col+1<KB)? wp[1]:0.f;
                v.z = (col+2<KB)? wp[2]:0.f;
                v.w = (col+3<KB)? wp[3]:0.f;
            }
            *(float4*)(&Ws[r][c]) = v;
        }
        __syncthreads();
        #pragma unroll
        for (int kk=0;kk<GBK;kk++){
            const float4 av = *(const float4*)(&As[kk][tr<<2]);
            const float4 wv = *(const float4*)(&Ws[kk][tc<<2]);
            acc[0][0]+=av.x*wv.x; acc[0][1]+=av.x*wv.y; acc[0][2]+=av.x*wv.z; acc[0][3]+=av.x*wv.w;
            acc[1][0]+=av.y*wv.x; acc[1][1]+=av.y*wv.y; acc[1][2]+=av.y*wv.z; acc[1][3]+=av.y*wv.w;
            acc[2][0]+=av.z*wv.x; acc[2][1]+=av.z*wv.y; acc[2][2]+=av.z*wv.z; acc[2][3]+=av.z*wv.w;
            acc[3][0]+=av.w*wv.x; acc[3][1]+=av.w*wv.y; acc[3][2]+=av.w*wv.z; acc[3][3]+=av.w*wv.w;
        }
        __syncthreads();
    }
    #pragma unroll
    for (int ii=0;ii<4;ii++){
        int row = bm + (tr<<2) + ii;
        if (row >= N) continue;
        #pragma unroll
        for (int jj=0;jj<4;jj++){
            int col = bn + (tc<<2) + jj;
            if (col >= KB) continue;
            float v = acc[ii][jj];
            if (bias) v += bias[col];
            if (ACT==1) v = gelu_t(v);
            if (RES) v += resid[(size_t)row*KB + col];
            C[(size_t)row*KB + col] = v;
        }
    }
}

// ---------------- attention (bf16 in/out, fp32 math); wave-parallel softmax ----------------
__global__ void attn_kernel(const us* __restrict__ qkv, us* __restrict__ o){
    int bb = blockIdx.x >> 3;
    int h  = blockIdx.x & 7;
    __shared__ float qs[49][33], ks[49][33], vs[49][33];
    __shared__ float ss[49][49];
    const us* base = qkv + (size_t)bb*T_*768 + h*32;
    for (int i = threadIdx.x; i < 49*16; i += 256){
        int t = i>>4, d2 = i&15;
        unsigned int q = *(const unsigned int*)(base + (size_t)t*768 + d2*2);
        unsigned int k = *(const unsigned int*)(base + (size_t)t*768 + 256 + d2*2);
        unsigned int v = *(const unsigned int*)(base + (size_t)t*768 + 512 + d2*2);
        qs[t][d2*2] = bf2f((us)(q&0xffff)); qs[t][d2*2+1] = bf2f((us)(q>>16));
        ks[t][d2*2] = bf2f((us)(k&0xffff)); ks[t][d2*2+1] = bf2f((us)(k>>16));
        vs[t][d2*2] = bf2f((us)(v&0xffff)); vs[t][d2*2+1] = bf2f((us)(v>>16));
    }
    __syncthreads();
    for (int i = threadIdx.x; i < 49*49; i += 256){
        int r = i/49, c = i%49;
        float acc = 0.f;
        #pragma unroll
        for (int d=0;d<32;d++) acc += qs[r][d]*ks[c][d];
        ss[r][c] = acc*0.17677669529663687f;
    }
    __syncthreads();
    if (threadIdx.x < 196){
        int r = threadIdx.x>>2, q = threadIdx.x&3;
        float m = -1e30f;
        for (int c=q; c<49; c+=4) m = fmaxf(m, ss[r][c]);
        m = fmaxf(m, __shfl_xor(m,1,64)); m = fmaxf(m, __shfl_xor(m,2,64));
        float sum = 0.f;
        for (int c=q; c<49; c+=4){ float e = __expf(ss[r][c]-m); ss[r][c]=e; sum+=e; }
        sum += __shfl_xor(sum,1,64); sum += __shfl_xor(sum,2,64);
        float inv = __fdividef(1.0f, sum);
        for (int c=q; c<49; c+=4) ss[r][c] *= inv;
    }
    __syncthreads();
    for (int i = threadIdx.x; i < 49*32; i += 256){
        int r = i>>5, d = i&31;
        float acc = 0.f;
        for (int c=0;c<49;c++) acc += ss[r][c]*vs[c][d];
        o[((size_t)bb*T_ + r)*256 + h*32 + d] = f2bf(acc);
    }
}

// ---------------- score head (vectorized bf16 loads) ----------------
__global__ void score_kernel(const us* __restrict__ s2, const float* __restrict__ w3,
                             const float* __restrict__ b3, float* __restrict__ sc,
                             float* __restrict__ pred, int layer, int row0, int nrows){
    int lr = blockIdx.x*256 + threadIdx.x;
    if (lr >= nrows) return;
    int row = row0 + lr;
    int s = row / BT_;
    int r = row % BT_;
    int b = r / T_;
    int t = r % T_;
    const uint4* xv = (const uint4*)(s2 + (size_t)lr*128);
    float l0 = b3[0], l1 = b3[1];
    #pragma unroll
    for (int q=0;q<16;q++){
        uint4 u = xv[q];
        unsigned int uu[4] = {u.x,u.y,u.z,u.w};
        #pragma unroll
        for (int e=0;e<4;e++){
            float fa = bf2f((us)(uu[e]&0xffff));
            float fb = bf2f((us)(uu[e]>>16));
            int d = q*8 + e*2;
            l0 += fa*w3[d*2]     + fb*w3[(d+1)*2];
            l1 += fa*w3[d*2+1]   + fb*w3[(d+1)*2+1];
        }
    }
    float m = fmaxf(l0,l1);
    float e0 = __expf(l0-m), e1 = __expf(l1-m);
    float sc0 = __fdividef(e0, e0+e1);
    sc[b*(5*T_) + s*T_ + t] = sc0;
    pred[(size_t)b*(L_*5*T_) + (size_t)layer*(5*T_) + s*T_ + t] = sc0;
}

// ---------------- image fusion (both slots, in-place) ----------------
__global__ void img_fuse_kernel(float* __restrict__ X, const float* __restrict__ sc){
    size_t i = (size_t)blockIdx.x*256 + threadIdx.x;
    if (i >= (size_t)BT_*64) return;
    int row = (int)(i>>6), d4 = (int)(i&63);
    int b = row / T_, t = row % T_;
    float s0 = sc[b*(5*T_) + t];
    float s1 = sc[b*(5*T_) + T_ + t];
    float fm0  = (s0 > THRESH)? 1.f : 0.f;
    float fnm0 = -fm0 - 1.f;
    float fm1  = (s1 > THRESH)? 1.f : 0.f;
    float fnm1 = -fm1 - 1.f;
    float4* p0 = ((float4*)(X + (size_t)row*D_)) + d4;
    float4* p1 = ((float4*)(X + ((size_t)BT_ + row)*D_)) + d4;
    float4 a0 = *p0, a1 = *p1;
    float4 r0, r1;
    r0.x = a0.x*fm0 + a1.x*fnm0;  r0.y = a0.y*fm0 + a1.y*fnm0;
    r0.z = a0.z*fm0 + a1.z*fnm0;  r0.w = a0.w*fm0 + a1.w*fnm0;
    r1.x = a1.x*fm1 + a0.x*fnm1;  r1.y = a1.y*fm1 + a0.y*fnm1;
    r1.z = a1.z*fm1 + a0.z*fnm1;  r1.w = a1.w*fm1 + a0.w*fnm1;
    *p0 = r0; *p1 = r1;
}

// ---------------- gather 6 (j,k2) streams: rows [j*3R + k2*R + r] ----------------
__global__ void gather6_kernel(const float* __restrict__ X, const int* __restrict__ idx,
                               us* __restrict__ g, int off, int R){
    size_t i = (size_t)blockIdx.x*256 + threadIdx.x;
    if (i >= (size_t)6*R*64) return;
    int vrow = (int)(i>>6), d4 = (int)(i&63);
    int s = vrow / R, r = vrow % R;
    int j = s / 3, k2 = s % 3;
    int grow = off + r;
    int b = grow / T_;
    int src = idx[(size_t)(k2*2+j)*BT_ + grow];
    float4 v = ((const float4*)(X + ((size_t)j*BT_ + (size_t)b*T_ + src)*D_))[d4];
    ushort4 o4; o4.x=f2bf(v.x); o4.y=f2bf(v.y); o4.z=f2bf(v.z); o4.w=f2bf(v.w);
    ((ushort4*)(g + (size_t)vrow*D_))[d4] = o4;
}

// ---------------- point fusion from summed PO [3R,256] (bf16) ----------------
__global__ void pt_fuse3_kernel(float* __restrict__ X, const us* __restrict__ PO,
                                const float* __restrict__ sc, int off, int R){
    size_t i = (size_t)blockIdx.x*256 + threadIdx.x;
    if (i >= (size_t)3*R*64) return;
    int vrow = (int)(i>>6), d4 = (int)(i&63);
    int k2 = vrow / R, r = vrow % R;
    int grow = off + r;
    int b = grow / T_, t = grow % T_;
    float s = sc[b*(5*T_) + (2+k2)*T_ + t];
    float fm  = (s > THRESH)? 1.f : 0.f;
    float fnm = -fm - 1.f;
    float4* xp = ((float4*)(X + ((size_t)(2+k2)*BT_ + grow)*D_)) + d4;
    float4 a = *xp;
    uint2 u = ((const uint2*)(PO + (size_t)vrow*D_))[d4];
    float p0 = bf2f((us)(u.x&0xffff)), p1 = bf2f((us)(u.x>>16));
    float p2 = bf2f((us)(u.y&0xffff)), p3 = bf2f((us)(u.y>>16));
    float4 rr;
    rr.x = a.x*fm + p0*fnm;
    rr.y = a.y*fm + p1*fnm;
    rr.z = a.z*fm + p2*fnm;
    rr.w = a.w*fm + p3*fnm;
    *xp = rr;
}

// ---------------- max-pool over 245 tokens (float4 per thread) ----------------
__global__ void pool_kernel(const float* __restrict__ x, float* __restrict__ p){
    int i = blockIdx.x*256 + threadIdx.x;
    if (i >= B_*64) return;
    int b = i>>6, d4 = i&63;
    float4 m; m.x=m.y=m.z=m.w=-3.4e38f;
    for (int s=0;s<5;s++){
        const float4* bp = ((const float4*)(x + ((size_t)s*BT_ + (size_t)b*T_)*D_)) + d4;
        for (int t=0;t<T_;t++){
            float4 v = bp[(size_t)t*64];
            m.x=fmaxf(m.x,v.x); m.y=fmaxf(m.y,v.y); m.z=fmaxf(m.z,v.z); m.w=fmaxf(m.w,v.w);
        }
    }
    ((float4*)p)[i] = m;
}

static inline int cdiv(int a, int b){ return (a+b-1)/b; }

extern "C" void kernel_launch(void* const* d_in, const int* in_sizes, int n_in,
                              void* d_out, int out_size, void* d_ws, size_t ws_size,
                              hipStream_t stream)
{
    const float* in_img0 = (const float*)d_in[0];
    const float* in_img1 = (const float*)d_in[1];
    const float* in_p0   = (const float*)d_in[2];
    const float* in_p1   = (const float*)d_in[3];
    const float* in_p2   = (const float*)d_in[4];
    const int*   in_idx  = (const int*)d_in[5];
    const float* enc_ln1g = (const float*)d_in[6];
    const float* enc_ln1b = (const float*)d_in[7];
    const float* enc_wqkv = (const float*)d_in[8];
    const float* enc_wo   = (const float*)d_in[9];
    const float* enc_bo   = (const float*)d_in[10];
    const float* enc_ln2g = (const float*)d_in[11];
    const float* enc_ln2b = (const float*)d_in[12];
    const float* enc_w1   = (const float*)d_in[13];
    const float* enc_b1   = (const float*)d_in[14];
    const float* enc_w2   = (const float*)d_in[15];
    const float* enc_b2   = (const float*)d_in[16];
    const float* sc_lng   = (const float*)d_in[17];
    const float* sc_lnb   = (const float*)d_in[18];
    const float* sc_w1    = (const float*)d_in[19];
    const float* sc_b1    = (const float*)d_in[20];
    const float* sc_w2    = (const float*)d_in[21];
    const float* sc_b2    = (const float*)d_in[22];
    const float* sc_w3    = (const float*)d_in[23];
    const float* sc_b3    = (const float*)d_in[24];
    const float* pm_w1    = (const float*)d_in[25];
    const float* pm_b1    = (const float*)d_in[26];
    const float* pm_w2    = (const float*)d_in[27];
    const float* pm_b2    = (const float*)d_in[28];
    const float* pm_w3    = (const float*)d_in[29];
    const float* pm_b3    = (const float*)d_in[30];
    const float* hd_lng   = (const float*)d_in[31];
    const float* hd_lnb   = (const float*)d_in[32];
    const float* hd_w1    = (const float*)d_in[33];
    const float* hd_b1    = (const float*)d_in[34];
    const float* hd_w2    = (const float*)d_in[35];
    const float* hd_b2    = (const float*)d_in[36];

    // ---------------- workspace layout ----------------
    char* p = (char*)d_ws;
    float* X   = (float*)p;  p += (size_t)5*BT_*D_*4;
    float* SCb = (float*)p;  p += (size_t)B_*5*T_*4;
    us* LNB  = (us*)p; p += (size_t)NTOK5*D_*2;          // LN output, all 5BT rows
    us* WQKV = (us*)p; p += (size_t)8*768*256*2;
    us* WWO  = (us*)p; p += (size_t)8*256*256*2;
    us* WW1  = (us*)p; p += (size_t)8*1024*256*2;
    us* WW2  = (us*)p; p += (size_t)8*256*1024*2;
    us* WS1  = (us*)p; p += (size_t)4*256*256*2;
    us* WS2  = (us*)p; p += (size_t)4*128*256*2;
    us* WP1  = (us*)p; p += (size_t)4*1024*256*2;
    us* WP2  = (us*)p; p += (size_t)4*1024*1024*2;
    us* WP3  = (us*)p; p += (size_t)4*256*1024*2;
    float* B3x2 = (float*)p; p += (size_t)4*256*4;
    float* POOL = (float*)p; p += (size_t)B_*256*4;
    float* HLN  = (float*)p; p += (size_t)B_*256*4;
    float* HMID = (float*)p; p += (size_t)B_*1024*4;
    size_t fixed = (size_t)(p - (char*)d_ws);
    long long pool = (long long)ws_size - (long long)fixed;
    if (pool < 0) pool = 0;
    // per-row scratch bytes: encoder 2560, score 768, patch 18432
    auto chunkOf = [&](long long perRow, int maxRows)->int{
        long long c = pool / perRow;
        c = (c / T_) * T_;
        if (c < T_) c = T_;
        if (c > maxRows) c = maxRows;
        return (int)c;
    };
    int Cenc = chunkOf(2560, 3*BT_);
    int Csc  = chunkOf(768, NTOK5);
    int Cpat = chunkOf(18432, BT_);
    char* pb = p;
    us* eR2 = (us*)pb;                                    // [Cenc,1024] (QKV 768 / FFN mid)
    us* eR3 = (us*)(pb + (size_t)Cenc*2048);              // [Cenc,256]
    us* sS1 = (us*)pb;                                    // [Csc,256]
    us* sS2 = (us*)(pb + (size_t)Csc*512);                // [Csc,128]
    us*    pP1 = (us*)pb;
    us*    pPO = (us*)pb;                                 // [3R,256] bf16, aliases pP1 (dead)
    us*    pS  = (us*)(pb + (size_t)Cpat*12288);
    us*    pG  = pS;

    float* out_smplx = (float*)d_out;
    float* out_pred  = out_smplx + (size_t)B_*OUT_;

    // ---------------- weight transpose + bf16 convert ----------------
    wtrans_kernel<<<dim3(cdiv(768,32), cdiv(256,32), 8),256,0,stream>>>(enc_wqkv, WQKV, 256, 768);
    wtrans_kernel<<<dim3(cdiv(256,32), cdiv(256,32), 8),256,0,stream>>>(enc_wo,   WWO,  256, 256);
    wtrans_kernel<<<dim3(cdiv(1024,32),cdiv(256,32), 8),256,0,stream>>>(enc_w1,   WW1,  256, 1024);
    wtrans_kernel<<<dim3(cdiv(256,32), cdiv(1024,32),8),256,0,stream>>>(enc_w2,   WW2,  1024,256);
    wtrans_kernel<<<dim3(cdiv(256,32), cdiv(256,32), 4),256,0,stream>>>(sc_w1,    WS1,  256, 256);
    wtrans_kernel<<<dim3(cdiv(128,32), cdiv(256,32), 4),256,0,stream>>>(sc_w2,    WS2,  256, 128);
    wtrans_kernel<<<dim3(cdiv(1024,32),cdiv(256,32), 4),256,0,stream>>>(pm_w1,    WP1,  256, 1024);
    wtrans_kernel<<<dim3(cdiv(1024,32),cdiv(1024,32),4),256,0,stream>>>(pm_w2,    WP2,  1024,1024);
    wtrans_kernel<<<dim3(cdiv(256,32), cdiv(1024,32),4),256,0,stream>>>(pm_w3,    WP3,  1024,256);
    dblb_kernel<<<4,256,0,stream>>>(pm_b3, B3x2, 4*256);

    copy_in_kernel<<<cdiv(NTOK5*64,256), 256, 0, stream>>>(in_img0,in_img1,in_p0,in_p1,in_p2, X);

    for (int i=0;i<L_;i++){
        // ---------- ln1 over ALL streams (one dispatch) ----------
        ln_enc_kernel<<<cdiv(NTOK5,4),256,0,stream>>>(X,
            enc_ln1g + (size_t)i*D_, enc_ln1b + (size_t)i*D_,
            enc_ln1g + (size_t)(L_+i)*D_, enc_ln1b + (size_t)(L_+i)*D_, LNB);
        // ---------- attention half (per group/chunk) ----------
        for (int grp=0; grp<2; grp++){
            int base  = (grp==0)? 0 : 2*BT_;
            int total = (grp==0)? 2*BT_ : 3*BT_;
            size_t wi = (size_t)(grp*L_ + i);
            for (int off=0; off<total; off+=Cenc){
                int R = total-off < Cenc ? total-off : Cenc;
                float* Xp = X + (size_t)(base+off)*D_;
                mfma_gemm<0,0,true><<<dim3(6, cdiv(R,128)),256,0,stream>>>(
                    LNB + (size_t)(base+off)*D_, WQKV + wi*768*256, nullptr, nullptr, eR2, R, 768, 256);
                attn_kernel<<<(R/T_)*8,256,0,stream>>>(eR2, eR3);
                mfma_gemm<0,1,false><<<dim3(2, cdiv(R,128)),256,0,stream>>>(
                    eR3, WWO + wi*256*256, enc_bo + wi*D_, Xp, Xp, R, 256, 256);
            }
        }
        // ---------- ln2 over ALL streams ----------
        ln_enc_kernel<<<cdiv(NTOK5,4),256,0,stream>>>(X,
            enc_ln2g + (size_t)i*D_, enc_ln2b + (size_t)i*D_,
            enc_ln2g + (size_t)(L_+i)*D_, enc_ln2b + (size_t)(L_+i)*D_, LNB);
        // ---------- FFN half (per group/chunk) ----------
        for (int grp=0; grp<2; grp++){
            int base  = (grp==0)? 0 : 2*BT_;
            int total = (grp==0)? 2*BT_ : 3*BT_;
            size_t wi = (size_t)(grp*L_ + i);
            for (int off=0; off<total; off+=Cenc){
                int R = total-off < Cenc ? total-off : Cenc;
                float* Xp = X + (size_t)(base+off)*D_;
                mfma_gemm<1,0,true><<<dim3(8, cdiv(R,128)),256,0,stream>>>(
                    LNB + (size_t)(base+off)*D_, WW1 + wi*1024*256, enc_b1 + wi*M_, nullptr, eR2, R, 1024, 256);
                mfma_gemm<0,1,false><<<dim3(2, cdiv(R,128)),256,0,stream>>>(
                    eR2, WW2 + wi*256*1024, enc_b2 + wi*D_, Xp, Xp, R, 256, 1024);
            }
        }
        // ---------- score net ----------
        ln_kernel<true><<<cdiv(NTOK5,4),256,0,stream>>>(X,
            sc_lng+(size_t)i*D_, sc_lnb+(size_t)i*D_, LNB, NTOK5);
        for (int off=0; off<NTOK5; off+=Csc){
            int R = NTOK5-off < Csc ? NTOK5-off : Csc;
            mfma_gemm<1,0,true><<<dim3(2, cdiv(R,128)),256,0,stream>>>(
                LNB + (size_t)off*D_, WS1 + (size_t)i*256*256, sc_b1+(size_t)i*D_, nullptr, sS1, R, 256, 256);
            mfma_gemm<1,0,true><<<dim3(1, cdiv(R,128)),256,0,stream>>>(
                sS1, WS2 + (size_t)i*128*256, sc_b2+(size_t)i*128, nullptr, sS2, R, 128, 256);
            score_kernel<<<cdiv(R,256),256,0,stream>>>(
                sS2, sc_w3+(size_t)i*256, sc_b3+(size_t)i*2, SCb, out_pred, i, off, R);
        }
        // ---------- patch MLPs (j-split, merged P3) + point fusion ----------
        for (int off=0; off<BT_; off+=Cpat){
            int R = BT_-off < Cpat ? BT_-off : Cpat;
            gather6_kernel<<<cdiv(6*R*64,256),256,0,stream>>>(X, in_idx, pG, off, R);
            mfma_gemm<1,0,true><<<dim3(8, cdiv(6*R,128)),256,0,stream>>>(
                pG, WP1 + (size_t)i*1024*256, pm_b1+(size_t)i*M_, nullptr, pP1, 6*R, 1024, 256);
            mfma_gemm<1,0,true><<<dim3(8, cdiv(3*R,128)),256,0,stream>>>(
                pP1, WP2 + (size_t)i*1024*1024, pm_b2+(size_t)i*M_, nullptr, pS, 3*R, 1024, 1024);
            mfma_gemm<1,2,true><<<dim3(8, cdiv(3*R,128)),256,0,stream>>>(
                pP1 + (size_t)3*R*1024, WP2 + (size_t)i*1024*1024, pm_b2+(size_t)i*M_, pS, pS, 3*R, 1024, 1024);
            mfma_gemm<0,0,true><<<dim3(2, cdiv(3*R,128)),256,0,stream>>>(
                pS, WP3 + (size_t)i*256*1024, B3x2+(size_t)i*256, nullptr, pPO, 3*R, 256, 1024);
            pt_fuse3_kernel<<<cdiv(3*R*64,256),256,0,stream>>>(X, pPO, SCb, off, R);
        }
        // ---------- image fusion LAST ----------
        img_fuse_kernel<<<cdiv(BT_*64,256),256,0,stream>>>(X, SCb);
    }
    // ---------- head (fp32) ----------
    pool_kernel<<<cdiv(B_*64,256),256,0,stream>>>(X, POOL);
    ln_kernel<false><<<cdiv(B_,4),256,0,stream>>>(POOL, hd_lng, hd_lnb, HLN, B_);
    gemm_kernel<1,false><<<dim3(16, cdiv(B_,64)),256,0,stream>>>(
        HLN, hd_w1, hd_b1, nullptr, HMID, B_, D_, M_);
    gemm_kernel<0,false><<<dim3(3, cdiv(B_,64)),256,0,stream>>>(
        HMID, hd_w2, hd_b2, nullptr, out_smplx, B_, M_, OUT_);
}

// Round 15
// 9198.804 us; speedup vs baseline: 1.2339x; 1.2339x over previous
//
#include <hip/hip_runtime.h>
#include <math.h>

#define B_ 512
#define T_ 49
#define D_ 256
#define M_ 1024
#define L_ 4
#define OUT_ 151
#define BT_ 25088            // B_*T_
#define NTOK5 (5*BT_)
#define THRESH 0.02f

typedef __bf16 bf16x8 __attribute__((ext_vector_type(8)));
typedef float f32x4 __attribute__((ext_vector_type(4)));
typedef unsigned short us;

__device__ __forceinline__ float gelu_t(float x){
    float u = 0.7978845608028654f * x * (1.0f + 0.044715f*x*x);
    float e = __expf(-2.0f*u);
    return __fdividef(x, 1.0f + e);
}
__device__ __forceinline__ us f2bf(float f){
    unsigned int u = __float_as_uint(f);
    u += 0x7fffu + ((u>>16)&1u);          // RNE
    return (us)(u>>16);
}
__device__ __forceinline__ float bf2f(us h){
    return __uint_as_float(((unsigned int)h)<<16);
}
__device__ __forceinline__ void gload16(const void* g, void* l){
    __builtin_amdgcn_global_load_lds(
        (const __attribute__((address_space(1))) void*)g,
        (__attribute__((address_space(3))) void*)l, 16, 0, 0);
}

// ---------------- copy 5 input streams into contiguous X buffer ----------------
__global__ void copy_in_kernel(const float* __restrict__ a0, const float* __restrict__ a1,
                               const float* __restrict__ a2, const float* __restrict__ a3,
                               const float* __restrict__ a4, float* __restrict__ dst){
    size_t i = (size_t)blockIdx.x*256 + threadIdx.x;
    if (i >= (size_t)NTOK5*64) return;
    int slot = (int)(i / ((size_t)BT_*64));
    size_t off = i % ((size_t)BT_*64);
    const float* src = slot==0?a0: slot==1?a1: slot==2?a2: slot==3?a3: a4;
    ((float4*)dst)[i] = ((const float4*)src)[off];
}

// ---------------- double bias (for linear-merged P3) ----------------
__global__ void dblb_kernel(const float* __restrict__ b, float* __restrict__ o, int n){
    int i = blockIdx.x*256 + threadIdx.x;
    if (i < n) o[i] = 2.0f*b[i];
}

// ---------------- LayerNorm D=256, 4 rows/block; OBF: bf16 or fp32 out ----------------
template<bool OBF>
__global__ void ln_kernel(const float* __restrict__ x, const float* __restrict__ g,
                          const float* __restrict__ b, void* __restrict__ y, int nrows){
    int row = blockIdx.x*4 + (threadIdx.x>>6);
    if (row >= nrows) return;
    int lane = threadIdx.x & 63;
    float4 v = ((const float4*)(x + (size_t)row*D_))[lane];
    float s  = v.x+v.y+v.z+v.w;
    float sq = v.x*v.x + v.y*v.y + v.z*v.z + v.w*v.w;
    #pragma unroll
    for (int o=32;o;o>>=1){ s += __shfl_xor(s,o,64); sq += __shfl_xor(sq,o,64); }
    float mu = s*(1.0f/256.0f);
    float rstd = rsqrtf(sq*(1.0f/256.0f) - mu*mu + 1e-5f);
    float4 gv = ((const float4*)g)[lane];
    float4 bv = ((const float4*)b)[lane];
    float o0 = (v.x-mu)*rstd*gv.x + bv.x;
    float o1 = (v.y-mu)*rstd*gv.y + bv.y;
    float o2 = (v.z-mu)*rstd*gv.z + bv.z;
    float o3 = (v.w-mu)*rstd*gv.w + bv.w;
    if (OBF){
        ushort4 o4; o4.x=f2bf(o0); o4.y=f2bf(o1); o4.z=f2bf(o2); o4.w=f2bf(o3);
        ((ushort4*)((us*)y + (size_t)row*D_))[lane] = o4;
    } else {
        float4 o4; o4.x=o0; o4.y=o1; o4.z=o2; o4.w=o3;
        ((float4*)((float*)y + (size_t)row*D_))[lane] = o4;
    }
}

// ---------------- weight transpose+convert: W[g][K][N] fp32 -> Wt[g][N][K] bf16 ----------------
__global__ void wtrans_kernel(const float* __restrict__ W, us* __restrict__ Wt,
                              int K, int N){
    int g = blockIdx.z;
    __shared__ float t[32][33];
    int k0 = blockIdx.y*32, n0 = blockIdx.x*32;
    int tx = threadIdx.x&31, ty = threadIdx.x>>5;
    for (int r=ty; r<32; r+=8){
        int k = k0+r, n = n0+tx;
        t[r][tx] = (k<K && n<N) ? W[(size_t)g*K*N + (size_t)k*N + n] : 0.f;
    }
    __syncthreads();
    for (int r=ty; r<32; r+=8){
        int n = n0+r, k = k0+tx;
        if (n<N && k<K) Wt[(size_t)g*N*K + (size_t)n*K + k] = f2bf(t[tx][r]);
    }
}

__device__ __forceinline__ void gemm_compute(const us* As, const us* Bs,
        int wr, int wc, int lr, int kg, f32x4 (&acc)[4][4]){
    bf16x8 av[4], bv[4];
    #pragma unroll
    for (int mi=0;mi<4;mi++){
        int r = wr*64 + mi*16 + lr;
        av[mi] = *(const bf16x8*)(&As[r*32 + ((kg ^ ((r>>1)&3))<<3)]);
    }
    #pragma unroll
    for (int ni=0;ni<4;ni++){
        int c = wc*64 + ni*16 + lr;
        bv[ni] = *(const bf16x8*)(&Bs[c*32 + ((kg ^ ((c>>1)&3))<<3)]);
    }
    #pragma unroll
    for (int mi=0;mi<4;mi++)
        #pragma unroll
        for (int ni=0;ni<4;ni++)
            acc[mi][ni] = __builtin_amdgcn_mfma_f32_16x16x32_bf16(av[mi], bv[ni], acc[mi][ni], 0, 0, 0);
}

// ---------------- bf16 MFMA GEMM, 2-buf counted-vmcnt pipeline + XCD swizzle ----------------
// 128x128 tile, BK=32, 4 waves. RIN: 0 none, 1 fp32 resid, 2 bf16 resid (post-ACT).
// OBF && RIN==0: single-round bf16 LDS epilogue (1 barrier); else 2-round fp32.
template<int ACT, int RIN, bool OBF>
__global__ __launch_bounds__(256) void mfma_gemm(
    const us* __restrict__ A, const us* __restrict__ Wt,
    const float* __restrict__ bias, const void* __restrict__ resid,
    void* __restrict__ Cout, int Mr, int N, int K)
{
    __shared__ __align__(16) us SM[2*8192];            // 2 bufs x (A 8KB + B 8KB)
    const int nwg  = gridDim.x*gridDim.y;
    const int flat = blockIdx.y*gridDim.x + blockIdx.x;
    const int qq = nwg>>3, rr = nwg&7;
    const int xcd = flat&7, sidx = flat>>3;
    const int logical = (xcd<rr) ? (xcd*(qq+1)+sidx) : (rr*(qq+1)+(xcd-rr)*qq+sidx);
    const int bn = (logical % gridDim.x)*128;
    const int bm = (logical / gridDim.x)*128;
    const int tid = threadIdx.x;
    const int lane = tid&63, w = tid>>6;
    const int wr = w>>1, wc = w&1;
    const int lr = lane&15, kg = lane>>4;
    f32x4 acc[4][4] = {};

    const int j0 = tid, j1 = tid+256;
    const int row0 = j0>>2, row1 = j1>>2;
    const int k8s0 = (j0&3) ^ ((row0>>1)&3);
    const int k8s1 = (j1&3) ^ ((row1>>1)&3);
    int ga0 = bm+row0; if (ga0>=Mr) ga0=Mr-1;
    int ga1 = bm+row1; if (ga1>=Mr) ga1=Mr-1;
    int gb0 = bn+row0; if (gb0>=N) gb0=N-1;
    int gb1 = bn+row1; if (gb1>=N) gb1=N-1;
    const us* a0p = A  + (size_t)ga0*K + k8s0*8;
    const us* a1p = A  + (size_t)ga1*K + k8s1*8;
    const us* b0p = Wt + (size_t)gb0*K + k8s0*8;
    const us* b1p = Wt + (size_t)gb1*K + k8s1*8;

    const int nk = K >> 5;
    {
        us* b0 = SM;
        gload16(a0p, b0 + j0*8);
        gload16(a1p, b0 + j1*8);
        gload16(b0p, b0 + 4096 + j0*8);
        gload16(b1p, b0 + 4096 + j1*8);
        us* b1 = SM + 8192;
        gload16(a0p+32, b1 + j0*8);
        gload16(a1p+32, b1 + j1*8);
        gload16(b0p+32, b1 + 4096 + j0*8);
        gload16(b1p+32, b1 + 4096 + j1*8);
    }
    int cur = 0;
    for (int t=0; t<nk-1; ++t){
        asm volatile("s_waitcnt vmcnt(4)" ::: "memory");
        __builtin_amdgcn_s_barrier();
        __builtin_amdgcn_sched_barrier(0);
        const us* cbase = SM + cur*8192;
        gemm_compute(cbase, cbase+4096, wr, wc, lr, kg, acc);
        __builtin_amdgcn_sched_barrier(0);
        __builtin_amdgcn_s_barrier();
        if (t+2 < nk){
            us* nbase = SM + cur*8192;
            int k0 = (t+2)<<5;
            gload16(a0p+k0, nbase + j0*8);
            gload16(a1p+k0, nbase + j1*8);
            gload16(b0p+k0, nbase + 4096 + j0*8);
            gload16(b1p+k0, nbase + 4096 + j1*8);
        }
        cur ^= 1;
    }
    asm volatile("s_waitcnt vmcnt(0)" ::: "memory");
    __builtin_amdgcn_s_barrier();
    __builtin_amdgcn_sched_barrier(0);
    {
        const us* cbase = SM + cur*8192;
        gemm_compute(cbase, cbase+4096, wr, wc, lr, kg, acc);
    }
    __syncthreads();

    if (OBF && RIN==0){
        // ---- single-round bf16 epilogue: 128x128 us = 32KB, 1 barrier ----
        us* Cs16 = (us*)SM;
        #pragma unroll
        for (int mi=0;mi<4;mi++){
            #pragma unroll
            for (int ni=0;ni<4;ni++){
                #pragma unroll
                for (int r4=0;r4<4;r4++){
                    int row = wr*64 + mi*16 + kg*4 + r4;
                    int col = wc*64 + ni*16 + lr;
                    float v = acc[mi][ni][r4];
                    if (bias) v += bias[bn + col];
                    if (ACT==1) v = gelu_t(v);
                    int h = ((row>>2)&3) | ((row&1)<<2);
                    int punit = (col>>3) ^ h;
                    Cs16[row*128 + punit*8 + (col&7)] = f2bf(v);
                }
            }
        }
        __syncthreads();
        {
            int rbase = tid>>3, seg = tid&7;
            #pragma unroll
            for (int pass=0; pass<8; ++pass){
                int row = rbase + (pass>>1)*32;
                int half = pass&1;
                int grow = bm + row;
                if (grow < Mr){
                    int h = ((row>>2)&3) | ((row&1)<<2);
                    int punit = (half*8+seg) ^ h;
                    *(uint4*)((us*)Cout + (size_t)grow*N + bn + half*64 + seg*8)
                        = *(const uint4*)&Cs16[row*128 + punit*8];
                }
            }
        }
        return;
    }

    // ---- 2-round fp32 epilogue (RIN paths / fp32 out) ----
    float* Cs = (float*)SM;      // 64 x 128 f32 = 32KB
    #pragma unroll
    for (int er=0; er<2; er++){
        #pragma unroll
        for (int ml=0; ml<2; ml++){
            int mi = er*2 + ml;
            #pragma unroll
            for (int ni=0;ni<4;ni++){
                #pragma unroll
                for (int r4=0;r4<4;r4++){
                    int lrow = wr*32 + ml*16 + kg*4 + r4;
                    int lcol = wc*64 + ni*16 + lr;
                    int pcol = lcol ^ (((lrow>>2)&1)<<4);
                    float v = acc[mi][ni][r4];
                    if (bias) v += bias[bn + lcol];
                    if (ACT==1) v = gelu_t(v);
                    Cs[lrow*128 + pcol] = v;
                }
            }
        }
        __syncthreads();
        #pragma unroll
        for (int s=0; s<2; s++){
            int lrow = (tid>>3) + s*32;
            int tseg = tid&7;
            int pseg = tseg ^ ((lrow>>2)&1);
            const float4* src = (const float4*)&Cs[lrow*128 + pseg*16];
            float4 v0=src[0], v1=src[1], v2=src[2], v3=src[3];
            int grow = bm + (lrow>>5)*64 + (er*2 + ((lrow>>4)&1))*16 + (lrow&15);
            int gcol = bn + tseg*16;
            if (grow < Mr){
                if (RIN==1){
                    const float4* rp = (const float4*)((const float*)resid + (size_t)grow*N + gcol);
                    float4 r0=rp[0], r1=rp[1], r2=rp[2], r3=rp[3];
                    v0.x+=r0.x; v0.y+=r0.y; v0.z+=r0.z; v0.w+=r0.w;
                    v1.x+=r1.x; v1.y+=r1.y; v1.z+=r1.z; v1.w+=r1.w;
                    v2.x+=r2.x; v2.y+=r2.y; v2.z+=r2.z; v2.w+=r2.w;
                    v3.x+=r3.x; v3.y+=r3.y; v3.z+=r3.z; v3.w+=r3.w;
                } else if (RIN==2){
                    const uint4* rp = (const uint4*)((const us*)resid + (size_t)grow*N + gcol);
                    uint4 u0=rp[0], u1=rp[1];
                    v0.x+=bf2f((us)(u0.x&0xffff)); v0.y+=bf2f((us)(u0.x>>16));
                    v0.z+=bf2f((us)(u0.y&0xffff)); v0.w+=bf2f((us)(u0.y>>16));
                    v1.x+=bf2f((us)(u0.z&0xffff)); v1.y+=bf2f((us)(u0.z>>16));
                    v1.z+=bf2f((us)(u0.w&0xffff)); v1.w+=bf2f((us)(u0.w>>16));
                    v2.x+=bf2f((us)(u1.x&0xffff)); v2.y+=bf2f((us)(u1.x>>16));
                    v2.z+=bf2f((us)(u1.y&0xffff)); v2.w+=bf2f((us)(u1.y>>16));
                    v3.x+=bf2f((us)(u1.z&0xffff)); v3.y+=bf2f((us)(u1.z>>16));
                    v3.z+=bf2f((us)(u1.w&0xffff)); v3.w+=bf2f((us)(u1.w>>16));
                }
                if (OBF){
                    unsigned int w0 = (unsigned)f2bf(v0.x) | ((unsigned)f2bf(v0.y)<<16);
                    unsigned int w1 = (unsigned)f2bf(v0.z) | ((unsigned)f2bf(v0.w)<<16);
                    unsigned int w2 = (unsigned)f2bf(v1.x) | ((unsigned)f2bf(v1.y)<<16);
                    unsigned int w3 = (unsigned)f2bf(v1.z) | ((unsigned)f2bf(v1.w)<<16);
                    unsigned int w4 = (unsigned)f2bf(v2.x) | ((unsigned)f2bf(v2.y)<<16);
                    unsigned int w5 = (unsigned)f2bf(v2.z) | ((unsigned)f2bf(v2.w)<<16);
                    unsigned int w6 = (unsigned)f2bf(v3.x) | ((unsigned)f2bf(v3.y)<<16);
                    unsigned int w7 = (unsigned)f2bf(v3.z) | ((unsigned)f2bf(v3.w)<<16);
                    uint4* op = (uint4*)((us*)Cout + (size_t)grow*N + gcol);
                    uint4 u0; u0.x=w0; u0.y=w1; u0.z=w2; u0.w=w3;
                    uint4 u1; u1.x=w4; u1.y=w5; u1.z=w6; u1.w=w7;
                    op[0]=u0; op[1]=u1;
                } else {
                    float4* op = (float4*)((float*)Cout + (size_t)grow*N + gcol);
                    op[0]=v0; op[1]=v1; op[2]=v2; op[3]=v3;
                }
            }
        }
        __syncthreads();
    }
}

// ---------------- fp32 tiled GEMM (head only) ----------------
#define GBK 16
template<int ACT, bool RES>
__global__ void gemm_kernel(const float* __restrict__ A, const float* __restrict__ W,
                            const float* __restrict__ bias, const float* __restrict__ resid,
                            float* __restrict__ C, int N, int K, int KB){
    __shared__ float As[GBK][68];
    __shared__ float Ws[GBK][68];
    const int bm = blockIdx.y*64;
    const int bn = blockIdx.x*64;
    const int tid = threadIdx.x;
    const int tr = tid>>4, tc = tid&15;
    float acc[4][4] = {{0.f}};
    for (int k0 = 0; k0 < K; k0 += GBK){
        {
            int r = tid>>2;
            int c = (tid&3)<<2;
            int row = bm + r;
            float4 v = make_float4(0.f,0.f,0.f,0.f);
            if (row < N) v = *(const float4*)(A + (size_t)row*K + k0 + c);
            As[c+0][r]=v.x; As[c+1][r]=v.y; As[c+2][r]=v.z; As[c+3][r]=v.w;
        }
        {
            int r = tid>>4;
            int c = (tid&15)<<2;
            int col = bn + c;
            const float* wp = W + (size_t)(k0+r)*KB + col;
            float4 v;
            if ((KB & 3) == 0 && col + 3 < KB){
                v = *(const float4*)wp;
            } else {
                v.x = (col+0<KB)? wp[0]:0.f;
                v.y = (col+1<KB)? wp[1]:0.f;
                v.z = (col+2<KB)? wp[2]:0.f;
                v.w = (col+3<KB)? wp[3]:0.f;
            }
            *(float4*)(&Ws[r][c]) = v;
        }
        __syncthreads();
        #pragma unroll
        for (int kk=0;kk<GBK;kk++){
            const float4 av = *(const float4*)(&As[kk][tr<<2]);
            const float4 wv = *(const float4*)(&Ws[kk][tc<<2]);
            acc[0][0]+=av.x*wv.x; acc[0][1]+=av.x*wv.y; acc[0][2]+=av.x*wv.z; acc[0][3]+=av.x*wv.w;
            acc[1][0]+=av.y*wv.x; acc[1][1]+=av.y*wv.y; acc[1][2]+=av.y*wv.z; acc[1][3]+=av.y*wv.w;
            acc[2][0]+=av.z*wv.x; acc[2][1]+=av.z*wv.y; acc[2][2]+=av.z*wv.z; acc[2][3]+=av.z*wv.w;
            acc[3][0]+=av.w*wv.x; acc[3][1]+=av.w*wv.y; acc[3][2]+=av.w*wv.z; acc[3][3]+=av.w*wv.w;
        }
        __syncthreads();
    }
    #pragma unroll
    for (int ii=0;ii<4;ii++){
        int row = bm + (tr<<2) + ii;
        if (row >= N) continue;
        #pragma unroll
        for (int jj=0;jj<4;jj++){
            int col = bn + (tc<<2) + jj;
            if (col >= KB) continue;
            float v = acc[ii][jj];
            if (bias) v += bias[col];
            if (ACT==1) v = gelu_t(v);
            if (RES) v += resid[(size_t)row*KB + col];
            C[(size_t)row*KB + col] = v;
        }
    }
}

// ---------------- attention (bf16 in/out, fp32 math); wave-parallel softmax ----------------
__global__ void attn_kernel(const us* __restrict__ qkv, us* __restrict__ o){
    int bb = blockIdx.x >> 3;
    int h  = blockIdx.x & 7;
    __shared__ float qs[49][33], ks[49][33], vs[49][33];
    __shared__ float ss[49][49];
    const us* base = qkv + (size_t)bb*T_*768 + h*32;
    for (int i = threadIdx.x; i < 49*16; i += 256){
        int t = i>>4, d2 = i&15;
        unsigned int q = *(const unsigned int*)(base + (size_t)t*768 + d2*2);
        unsigned int k = *(const unsigned int*)(base + (size_t)t*768 + 256 + d2*2);
        unsigned int v = *(const unsigned int*)(base + (size_t)t*768 + 512 + d2*2);
        qs[t][d2*2] = bf2f((us)(q&0xffff)); qs[t][d2*2+1] = bf2f((us)(q>>16));
        ks[t][d2*2] = bf2f((us)(k&0xffff)); ks[t][d2*2+1] = bf2f((us)(k>>16));
        vs[t][d2*2] = bf2f((us)(v&0xffff)); vs[t][d2*2+1] = bf2f((us)(v>>16));
    }
    __syncthreads();
    for (int i = threadIdx.x; i < 49*49; i += 256){
        int r = i/49, c = i%49;
        float acc = 0.f;
        #pragma unroll
        for (int d=0;d<32;d++) acc += qs[r][d]*ks[c][d];
        ss[r][c] = acc*0.17677669529663687f;
    }
    __syncthreads();
    if (threadIdx.x < 196){
        int r = threadIdx.x>>2, q = threadIdx.x&3;
        float m = -1e30f;
        for (int c=q; c<49; c+=4) m = fmaxf(m, ss[r][c]);
        m = fmaxf(m, __shfl_xor(m,1,64)); m = fmaxf(m, __shfl_xor(m,2,64));
        float sum = 0.f;
        for (int c=q; c<49; c+=4){ float e = __expf(ss[r][c]-m); ss[r][c]=e; sum+=e; }
        sum += __shfl_xor(sum,1,64); sum += __shfl_xor(sum,2,64);
        float inv = __fdividef(1.0f, sum);
        for (int c=q; c<49; c+=4) ss[r][c] *= inv;
    }
    __syncthreads();
    for (int i = threadIdx.x; i < 49*32; i += 256){
        int r = i>>5, d = i&31;
        float acc = 0.f;
        for (int c=0;c<49;c++) acc += ss[r][c]*vs[c][d];
        o[((size_t)bb*T_ + r)*256 + h*32 + d] = f2bf(acc);
    }
}

// ---------------- score head (vectorized bf16 loads) ----------------
__global__ void score_kernel(const us* __restrict__ s2, const float* __restrict__ w3,
                             const float* __restrict__ b3, float* __restrict__ sc,
                             float* __restrict__ pred, int layer, int row0, int nrows){
    int lr = blockIdx.x*256 + threadIdx.x;
    if (lr >= nrows) return;
    int row = row0 + lr;
    int s = row / BT_;
    int r = row % BT_;
    int b = r / T_;
    int t = r % T_;
    const uint4* xv = (const uint4*)(s2 + (size_t)lr*128);
    float l0 = b3[0], l1 = b3[1];
    #pragma unroll
    for (int q=0;q<16;q++){
        uint4 u = xv[q];
        unsigned int uu[4] = {u.x,u.y,u.z,u.w};
        #pragma unroll
        for (int e=0;e<4;e++){
            float fa = bf2f((us)(uu[e]&0xffff));
            float fb = bf2f((us)(uu[e]>>16));
            int d = q*8 + e*2;
            l0 += fa*w3[d*2]     + fb*w3[(d+1)*2];
            l1 += fa*w3[d*2+1]   + fb*w3[(d+1)*2+1];
        }
    }
    float m = fmaxf(l0,l1);
    float e0 = __expf(l0-m), e1 = __expf(l1-m);
    float sc0 = __fdividef(e0, e0+e1);
    sc[b*(5*T_) + s*T_ + t] = sc0;
    pred[(size_t)b*(L_*5*T_) + (size_t)layer*(5*T_) + s*T_ + t] = sc0;
}

// ---------------- image fusion (both slots, in-place) ----------------
__global__ void img_fuse_kernel(float* __restrict__ X, const float* __restrict__ sc){
    size_t i = (size_t)blockIdx.x*256 + threadIdx.x;
    if (i >= (size_t)BT_*64) return;
    int row = (int)(i>>6), d4 = (int)(i&63);
    int b = row / T_, t = row % T_;
    float s0 = sc[b*(5*T_) + t];
    float s1 = sc[b*(5*T_) + T_ + t];
    float fm0  = (s0 > THRESH)? 1.f : 0.f;
    float fnm0 = -fm0 - 1.f;
    float fm1  = (s1 > THRESH)? 1.f : 0.f;
    float fnm1 = -fm1 - 1.f;
    float4* p0 = ((float4*)(X + (size_t)row*D_)) + d4;
    float4* p1 = ((float4*)(X + ((size_t)BT_ + row)*D_)) + d4;
    float4 a0 = *p0, a1 = *p1;
    float4 r0, r1;
    r0.x = a0.x*fm0 + a1.x*fnm0;  r0.y = a0.y*fm0 + a1.y*fnm0;
    r0.z = a0.z*fm0 + a1.z*fnm0;  r0.w = a0.w*fm0 + a1.w*fnm0;
    r1.x = a1.x*fm1 + a0.x*fnm1;  r1.y = a1.y*fm1 + a0.y*fnm1;
    r1.z = a1.z*fm1 + a0.z*fnm1;  r1.w = a1.w*fm1 + a0.w*fnm1;
    *p0 = r0; *p1 = r1;
}

// ---------------- gather 6 (j,k2) streams: rows [j*3R + k2*R + r] ----------------
__global__ void gather6_kernel(const float* __restrict__ X, const int* __restrict__ idx,
                               us* __restrict__ g, int off, int R){
    size_t i = (size_t)blockIdx.x*256 + threadIdx.x;
    if (i >= (size_t)6*R*64) return;
    int vrow = (int)(i>>6), d4 = (int)(i&63);
    int s = vrow / R, r = vrow % R;
    int j = s / 3, k2 = s % 3;
    int grow = off + r;
    int b = grow / T_;
    int src = idx[(size_t)(k2*2+j)*BT_ + grow];
    float4 v = ((const float4*)(X + ((size_t)j*BT_ + (size_t)b*T_ + src)*D_))[d4];
    ushort4 o4; o4.x=f2bf(v.x); o4.y=f2bf(v.y); o4.z=f2bf(v.z); o4.w=f2bf(v.w);
    ((ushort4*)(g + (size_t)vrow*D_))[d4] = o4;
}

// ---------------- point fusion from summed PO [3R,256] (bf16) ----------------
__global__ void pt_fuse3_kernel(float* __restrict__ X, const us* __restrict__ PO,
                                const float* __restrict__ sc, int off, int R){
    size_t i = (size_t)blockIdx.x*256 + threadIdx.x;
    if (i >= (size_t)3*R*64) return;
    int vrow = (int)(i>>6), d4 = (int)(i&63);
    int k2 = vrow / R, r = vrow % R;
    int grow = off + r;
    int b = grow / T_, t = grow % T_;
    float s = sc[b*(5*T_) + (2+k2)*T_ + t];
    float fm  = (s > THRESH)? 1.f : 0.f;
    float fnm = -fm - 1.f;
    float4* xp = ((float4*)(X + ((size_t)(2+k2)*BT_ + grow)*D_)) + d4;
    float4 a = *xp;
    uint2 u = ((const uint2*)(PO + (size_t)vrow*D_))[d4];
    float p0 = bf2f((us)(u.x&0xffff)), p1 = bf2f((us)(u.x>>16));
    float p2 = bf2f((us)(u.y&0xffff)), p3 = bf2f((us)(u.y>>16));
    float4 rr;
    rr.x = a.x*fm + p0*fnm;
    rr.y = a.y*fm + p1*fnm;
    rr.z = a.z*fm + p2*fnm;
    rr.w = a.w*fm + p3*fnm;
    *xp = rr;
}

// ---------------- max-pool over 245 tokens (float4 per thread) ----------------
__global__ void pool_kernel(const float* __restrict__ x, float* __restrict__ p){
    int i = blockIdx.x*256 + threadIdx.x;
    if (i >= B_*64) return;
    int b = i>>6, d4 = i&63;
    float4 m; m.x=m.y=m.z=m.w=-3.4e38f;
    for (int s=0;s<5;s++){
        const float4* bp = ((const float4*)(x + ((size_t)s*BT_ + (size_t)b*T_)*D_)) + d4;
        for (int t=0;t<T_;t++){
            float4 v = bp[(size_t)t*64];
            m.x=fmaxf(m.x,v.x); m.y=fmaxf(m.y,v.y); m.z=fmaxf(m.z,v.z); m.w=fmaxf(m.w,v.w);
        }
    }
    ((float4*)p)[i] = m;
}

static inline int cdiv(int a, int b){ return (a+b-1)/b; }

extern "C" void kernel_launch(void* const* d_in, const int* in_sizes, int n_in,
                              void* d_out, int out_size, void* d_ws, size_t ws_size,
                              hipStream_t stream)
{
    const float* in_img0 = (const float*)d_in[0];
    const float* in_img1 = (const float*)d_in[1];
    const float* in_p0   = (const float*)d_in[2];
    const float* in_p1   = (const float*)d_in[3];
    const float* in_p2   = (const float*)d_in[4];
    const int*   in_idx  = (const int*)d_in[5];
    const float* enc_ln1g = (const float*)d_in[6];
    const float* enc_ln1b = (const float*)d_in[7];
    const float* enc_wqkv = (const float*)d_in[8];
    const float* enc_wo   = (const float*)d_in[9];
    const float* enc_bo   = (const float*)d_in[10];
    const float* enc_ln2g = (const float*)d_in[11];
    const float* enc_ln2b = (const float*)d_in[12];
    const float* enc_w1   = (const float*)d_in[13];
    const float* enc_b1   = (const float*)d_in[14];
    const float* enc_w2   = (const float*)d_in[15];
    const float* enc_b2   = (const float*)d_in[16];
    const float* sc_lng   = (const float*)d_in[17];
    const float* sc_lnb   = (const float*)d_in[18];
    const float* sc_w1    = (const float*)d_in[19];
    const float* sc_b1    = (const float*)d_in[20];
    const float* sc_w2    = (const float*)d_in[21];
    const float* sc_b2    = (const float*)d_in[22];
    const float* sc_w3    = (const float*)d_in[23];
    const float* sc_b3    = (const float*)d_in[24];
    const float* pm_w1    = (const float*)d_in[25];
    const float* pm_b1    = (const float*)d_in[26];
    const float* pm_w2    = (const float*)d_in[27];
    const float* pm_b2    = (const float*)d_in[28];
    const float* pm_w3    = (const float*)d_in[29];
    const float* pm_b3    = (const float*)d_in[30];
    const float* hd_lng   = (const float*)d_in[31];
    const float* hd_lnb   = (const float*)d_in[32];
    const float* hd_w1    = (const float*)d_in[33];
    const float* hd_b1    = (const float*)d_in[34];
    const float* hd_w2    = (const float*)d_in[35];
    const float* hd_b2    = (const float*)d_in[36];

    // ---------------- workspace layout ----------------
    char* p = (char*)d_ws;
    float* X   = (float*)p;  p += (size_t)5*BT_*D_*4;
    float* SCb = (float*)p;  p += (size_t)B_*5*T_*4;
    us* WQKV = (us*)p; p += (size_t)8*768*256*2;
    us* WWO  = (us*)p; p += (size_t)8*256*256*2;
    us* WW1  = (us*)p; p += (size_t)8*1024*256*2;
    us* WW2  = (us*)p; p += (size_t)8*256*1024*2;
    us* WS1  = (us*)p; p += (size_t)4*256*256*2;
    us* WS2  = (us*)p; p += (size_t)4*128*256*2;
    us* WP1  = (us*)p; p += (size_t)4*1024*256*2;
    us* WP2  = (us*)p; p += (size_t)4*1024*1024*2;
    us* WP3  = (us*)p; p += (size_t)4*256*1024*2;
    float* B3x2 = (float*)p; p += (size_t)4*256*4;
    float* POOL = (float*)p; p += (size_t)B_*256*4;
    float* HLN  = (float*)p; p += (size_t)B_*256*4;
    float* HMID = (float*)p; p += (size_t)B_*1024*4;
    size_t fixed = (size_t)(p - (char*)d_ws);
    long long pool = (long long)ws_size - (long long)fixed;
    if (pool < 0) pool = 0;
    // per-row scratch bytes: encoder 3072, score 1280, patch 18432
    auto chunkOf = [&](long long perRow, int maxRows)->int{
        long long c = pool / perRow;
        c = (c / T_) * T_;
        if (c < T_) c = T_;
        if (c > maxRows) c = maxRows;
        return (int)c;
    };
    int Cenc = chunkOf(3072, 3*BT_);
    int Csc  = chunkOf(1280, NTOK5);
    int Cpat = chunkOf(18432, BT_);
    char* pb = p;
    us* eR1 = (us*)pb;
    us* eR2 = (us*)(pb + (size_t)Cenc*512);
    us* eR3 = (us*)(pb + (size_t)Cenc*512 + (size_t)Cenc*2048);
    us* sR1 = (us*)pb;
    us* sS1 = (us*)(pb + (size_t)Csc*512);
    us* sS2 = (us*)(pb + (size_t)Csc*1024);
    us*    pP1 = (us*)pb;
    us*    pPO = (us*)pb;                       // [3R,256] bf16, aliases pP1 (dead)
    us*    pS  = (us*)(pb + (size_t)Cpat*12288);
    us*    pG  = pS;

    float* out_smplx = (float*)d_out;
    float* out_pred  = out_smplx + (size_t)B_*OUT_;

    // ---------------- weight transpose + bf16 convert ----------------
    wtrans_kernel<<<dim3(cdiv(768,32), cdiv(256,32), 8),256,0,stream>>>(enc_wqkv, WQKV, 256, 768);
    wtrans_kernel<<<dim3(cdiv(256,32), cdiv(256,32), 8),256,0,stream>>>(enc_wo,   WWO,  256, 256);
    wtrans_kernel<<<dim3(cdiv(1024,32),cdiv(256,32), 8),256,0,stream>>>(enc_w1,   WW1,  256, 1024);
    wtrans_kernel<<<dim3(cdiv(256,32), cdiv(1024,32),8),256,0,stream>>>(enc_w2,   WW2,  1024,256);
    wtrans_kernel<<<dim3(cdiv(256,32), cdiv(256,32), 4),256,0,stream>>>(sc_w1,    WS1,  256, 256);
    wtrans_kernel<<<dim3(cdiv(128,32), cdiv(256,32), 4),256,0,stream>>>(sc_w2,    WS2,  256, 128);
    wtrans_kernel<<<dim3(cdiv(1024,32),cdiv(256,32), 4),256,0,stream>>>(pm_w1,    WP1,  256, 1024);
    wtrans_kernel<<<dim3(cdiv(1024,32),cdiv(1024,32),4),256,0,stream>>>(pm_w2,    WP2,  1024,1024);
    wtrans_kernel<<<dim3(cdiv(256,32), cdiv(1024,32),4),256,0,stream>>>(pm_w3,    WP3,  1024,256);
    dblb_kernel<<<4,256,0,stream>>>(pm_b3, B3x2, 4*256);

    copy_in_kernel<<<cdiv(NTOK5*64,256), 256, 0, stream>>>(in_img0,in_img1,in_p0,in_p1,in_p2, X);

    for (int i=0;i<L_;i++){
        // ---------- encoders ----------
        for (int grp=0; grp<2; grp++){
            int base  = (grp==0)? 0 : 2*BT_;
            int total = (grp==0)? 2*BT_ : 3*BT_;
            size_t wi = (size_t)(grp*L_ + i);
            for (int off=0; off<total; off+=Cenc){
                int R = total-off < Cenc ? total-off : Cenc;
                float* Xp = X + (size_t)(base+off)*D_;
                ln_kernel<true><<<cdiv(R,4),256,0,stream>>>(Xp, enc_ln1g+wi*D_, enc_ln1b+wi*D_, eR1, R);
                mfma_gemm<0,0,true><<<dim3(6, cdiv(R,128)),256,0,stream>>>(
                    eR1, WQKV + wi*768*256, nullptr, nullptr, eR2, R, 768, 256);
                attn_kernel<<<(R/T_)*8,256,0,stream>>>(eR2, eR3);
                mfma_gemm<0,1,false><<<dim3(2, cdiv(R,128)),256,0,stream>>>(
                    eR3, WWO + wi*256*256, enc_bo + wi*D_, Xp, Xp, R, 256, 256);
                ln_kernel<true><<<cdiv(R,4),256,0,stream>>>(Xp, enc_ln2g+wi*D_, enc_ln2b+wi*D_, eR1, R);
                mfma_gemm<1,0,true><<<dim3(8, cdiv(R,128)),256,0,stream>>>(
                    eR1, WW1 + wi*1024*256, enc_b1 + wi*M_, nullptr, eR2, R, 1024, 256);
                mfma_gemm<0,1,false><<<dim3(2, cdiv(R,128)),256,0,stream>>>(
                    eR2, WW2 + wi*256*1024, enc_b2 + wi*D_, Xp, Xp, R, 256, 1024);
            }
        }
        // ---------- score net ----------
        for (int off=0; off<NTOK5; off+=Csc){
            int R = NTOK5-off < Csc ? NTOK5-off : Csc;
            ln_kernel<true><<<cdiv(R,4),256,0,stream>>>(X + (size_t)off*D_,
                sc_lng+(size_t)i*D_, sc_lnb+(size_t)i*D_, sR1, R);
            mfma_gemm<1,0,true><<<dim3(2, cdiv(R,128)),256,0,stream>>>(
                sR1, WS1 + (size_t)i*256*256, sc_b1+(size_t)i*D_, nullptr, sS1, R, 256, 256);
            mfma_gemm<1,0,true><<<dim3(1, cdiv(R,128)),256,0,stream>>>(
                sS1, WS2 + (size_t)i*128*256, sc_b2+(size_t)i*128, nullptr, sS2, R, 128, 256);
            score_kernel<<<cdiv(R,256),256,0,stream>>>(
                sS2, sc_w3+(size_t)i*256, sc_b3+(size_t)i*2, SCb, out_pred, i, off, R);
        }
        // ---------- patch MLPs (j-split, merged P3) + point fusion ----------
        for (int off=0; off<BT_; off+=Cpat){
            int R = BT_-off < Cpat ? BT_-off : Cpat;
            gather6_kernel<<<cdiv(6*R*64,256),256,0,stream>>>(X, in_idx, pG, off, R);
            mfma_gemm<1,0,true><<<dim3(8, cdiv(6*R,128)),256,0,stream>>>(
                pG, WP1 + (size_t)i*1024*256, pm_b1+(size_t)i*M_, nullptr, pP1, 6*R, 1024, 256);
            mfma_gemm<1,0,true><<<dim3(8, cdiv(3*R,128)),256,0,stream>>>(
                pP1, WP2 + (size_t)i*1024*1024, pm_b2+(size_t)i*M_, nullptr, pS, 3*R, 1024, 1024);
            mfma_gemm<1,2,true><<<dim3(8, cdiv(3*R,128)),256,0,stream>>>(
                pP1 + (size_t)3*R*1024, WP2 + (size_t)i*1024*1024, pm_b2+(size_t)i*M_, pS, pS, 3*R, 1024, 1024);
            mfma_gemm<0,0,true><<<dim3(2, cdiv(3*R,128)),256,0,stream>>>(
                pS, WP3 + (size_t)i*256*1024, B3x2+(size_t)i*256, nullptr, pPO, 3*R, 256, 1024);
            pt_fuse3_kernel<<<cdiv(3*R*64,256),256,0,stream>>>(X, pPO, SCb, off, R);
        }
        // ---------- image fusion LAST ----------
        img_fuse_kernel<<<cdiv(BT_*64,256),256,0,stream>>>(X, SCb);
    }
    // ---------- head (fp32) ----------
    pool_kernel<<<cdiv(B_*64,256),256,0,stream>>>(X, POOL);
    ln_kernel<false><<<cdiv(B_,4),256,0,stream>>>(POOL, hd_lng, hd_lnb, HLN, B_);
    gemm_kernel<1,false><<<dim3(16, cdiv(B_,64)),256,0,stream>>>(
        HLN, hd_w1, hd_b1, nullptr, HMID, B_, D_, M_);
    gemm_kernel<0,false><<<dim3(3, cdiv(B_,64)),256,0,stream>>>(
        HMID, hd_w2, hd_b2, nullptr, out_smplx, B_, M_, OUT_);
}

// Round 16
// 6779.952 us; speedup vs baseline: 1.6741x; 1.3568x over previous
//
#include <hip/hip_runtime.h>
#include <math.h>

#define B_ 512
#define T_ 49
#define D_ 256
#define M_ 1024
#define L_ 4
#define OUT_ 151
#define BT_ 25088            // B_*T_
#define NTOK5 (5*BT_)
#define THRESH 0.02f

typedef __bf16 bf16x8 __attribute__((ext_vector_type(8)));
typedef float f32x4 __attribute__((ext_vector_type(4)));
typedef unsigned short us;

__device__ __forceinline__ float gelu_t(float x){
    float u = 0.7978845608028654f * x * (1.0f + 0.044715f*x*x);
    float e = __expf(-2.0f*u);
    return __fdividef(x, 1.0f + e);
}
__device__ __forceinline__ us f2bf(float f){
    unsigned int u = __float_as_uint(f);
    u += 0x7fffu + ((u>>16)&1u);          // RNE
    return (us)(u>>16);
}
__device__ __forceinline__ float bf2f(us h){
    return __uint_as_float(((unsigned int)h)<<16);
}
__device__ __forceinline__ void gload16(const void* g, void* l){
    __builtin_amdgcn_global_load_lds(
        (const __attribute__((address_space(1))) void*)g,
        (__attribute__((address_space(3))) void*)l, 16, 0, 0);
}

// ---------------- copy 5 input streams into contiguous X buffer ----------------
__global__ void copy_in_kernel(const float* __restrict__ a0, const float* __restrict__ a1,
                               const float* __restrict__ a2, const float* __restrict__ a3,
                               const float* __restrict__ a4, float* __restrict__ dst){
    size_t i = (size_t)blockIdx.x*256 + threadIdx.x;
    if (i >= (size_t)NTOK5*64) return;
    int slot = (int)(i / ((size_t)BT_*64));
    size_t off = i % ((size_t)BT_*64);
    const float* src = slot==0?a0: slot==1?a1: slot==2?a2: slot==3?a3: a4;
    ((float4*)dst)[i] = ((const float4*)src)[off];
}

// ---------------- fp32 rows -> bf16 rows (patch-MLP input conversion) ----------------
__global__ void xcvt_kernel(const float* __restrict__ x, us* __restrict__ y, int nrows){
    size_t i = (size_t)blockIdx.x*256 + threadIdx.x;   // over nrows*64 float4s
    if (i >= (size_t)nrows*64) return;
    float4 v = ((const float4*)x)[i];
    ushort4 o; o.x=f2bf(v.x); o.y=f2bf(v.y); o.z=f2bf(v.z); o.w=f2bf(v.w);
    ((ushort4*)y)[i] = o;
}

// ---------------- LayerNorm D=256, 4 rows/block; OBF: bf16 or fp32 out ----------------
template<bool OBF>
__global__ void ln_kernel(const float* __restrict__ x, const float* __restrict__ g,
                          const float* __restrict__ b, void* __restrict__ y, int nrows){
    int row = blockIdx.x*4 + (threadIdx.x>>6);
    if (row >= nrows) return;
    int lane = threadIdx.x & 63;
    float4 v = ((const float4*)(x + (size_t)row*D_))[lane];
    float s  = v.x+v.y+v.z+v.w;
    float sq = v.x*v.x + v.y*v.y + v.z*v.z + v.w*v.w;
    #pragma unroll
    for (int o=32;o;o>>=1){ s += __shfl_xor(s,o,64); sq += __shfl_xor(sq,o,64); }
    float mu = s*(1.0f/256.0f);
    float rstd = rsqrtf(sq*(1.0f/256.0f) - mu*mu + 1e-5f);
    float4 gv = ((const float4*)g)[lane];
    float4 bv = ((const float4*)b)[lane];
    float o0 = (v.x-mu)*rstd*gv.x + bv.x;
    float o1 = (v.y-mu)*rstd*gv.y + bv.y;
    float o2 = (v.z-mu)*rstd*gv.z + bv.z;
    float o3 = (v.w-mu)*rstd*gv.w + bv.w;
    if (OBF){
        ushort4 o4; o4.x=f2bf(o0); o4.y=f2bf(o1); o4.z=f2bf(o2); o4.w=f2bf(o3);
        ((ushort4*)((us*)y + (size_t)row*D_))[lane] = o4;
    } else {
        float4 o4; o4.x=o0; o4.y=o1; o4.z=o2; o4.w=o3;
        ((float4*)((float*)y + (size_t)row*D_))[lane] = o4;
    }
}

// ---------------- weight transpose+convert: W[g][K][N] fp32 -> Wt[g][N][K] bf16 ----------------
__global__ void wtrans_kernel(const float* __restrict__ W, us* __restrict__ Wt,
                              int K, int N){
    int g = blockIdx.z;
    __shared__ float t[32][33];
    int k0 = blockIdx.y*32, n0 = blockIdx.x*32;
    int tx = threadIdx.x&31, ty = threadIdx.x>>5;
    for (int r=ty; r<32; r+=8){
        int k = k0+r, n = n0+tx;
        t[r][tx] = (k<K && n<N) ? W[(size_t)g*K*N + (size_t)k*N + n] : 0.f;
    }
    __syncthreads();
    for (int r=ty; r<32; r+=8){
        int n = n0+r, k = k0+tx;
        if (n<N && k<K) Wt[(size_t)g*N*K + (size_t)n*K + k] = f2bf(t[tx][r]);
    }
}

__device__ __forceinline__ void gemm_compute(const us* As, const us* Bs,
        int wr, int wc, int lr, int kg, f32x4 (&acc)[4][4]){
    bf16x8 av[4], bv[4];
    #pragma unroll
    for (int mi=0;mi<4;mi++){
        int r = wr*64 + mi*16 + lr;
        av[mi] = *(const bf16x8*)(&As[r*32 + ((kg ^ ((r>>1)&3))<<3)]);
    }
    #pragma unroll
    for (int ni=0;ni<4;ni++){
        int c = wc*64 + ni*16 + lr;
        bv[ni] = *(const bf16x8*)(&Bs[c*32 + ((kg ^ ((c>>1)&3))<<3)]);
    }
    #pragma unroll
    for (int mi=0;mi<4;mi++)
        #pragma unroll
        for (int ni=0;ni<4;ni++)
            acc[mi][ni] = __builtin_amdgcn_mfma_f32_16x16x32_bf16(av[mi], bv[ni], acc[mi][ni], 0, 0, 0);
}

// ---------------- bf16 MFMA GEMM, 2-buf counted-vmcnt pipeline + XCD swizzle ----------------
// 128x128 tile, BK=32, 4 waves. RIN: 0 none, 1 fp32 resid, 2 bf16 resid (post-ACT).
// OBF && RIN==0: single-round bf16 LDS epilogue (1 barrier); else 2-round fp32.
template<int ACT, int RIN, bool OBF>
__global__ __launch_bounds__(256) void mfma_gemm(
    const us* __restrict__ A, const us* __restrict__ Wt,
    const float* __restrict__ bias, const void* __restrict__ resid,
    void* __restrict__ Cout, int Mr, int N, int K)
{
    __shared__ __align__(16) us SM[2*8192];            // 2 bufs x (A 8KB + B 8KB)
    const int nwg  = gridDim.x*gridDim.y;
    const int flat = blockIdx.y*gridDim.x + blockIdx.x;
    const int qq = nwg>>3, rr = nwg&7;
    const int xcd = flat&7, sidx = flat>>3;
    const int logical = (xcd<rr) ? (xcd*(qq+1)+sidx) : (rr*(qq+1)+(xcd-rr)*qq+sidx);
    const int bn = (logical % gridDim.x)*128;
    const int bm = (logical / gridDim.x)*128;
    const int tid = threadIdx.x;
    const int lane = tid&63, w = tid>>6;
    const int wr = w>>1, wc = w&1;
    const int lr = lane&15, kg = lane>>4;
    f32x4 acc[4][4] = {};

    const int j0 = tid, j1 = tid+256;
    const int row0 = j0>>2, row1 = j1>>2;
    const int k8s0 = (j0&3) ^ ((row0>>1)&3);
    const int k8s1 = (j1&3) ^ ((row1>>1)&3);
    int ga0 = bm+row0; if (ga0>=Mr) ga0=Mr-1;
    int ga1 = bm+row1; if (ga1>=Mr) ga1=Mr-1;
    int gb0 = bn+row0; if (gb0>=N) gb0=N-1;
    int gb1 = bn+row1; if (gb1>=N) gb1=N-1;
    const us* a0p = A  + (size_t)ga0*K + k8s0*8;
    const us* a1p = A  + (size_t)ga1*K + k8s1*8;
    const us* b0p = Wt + (size_t)gb0*K + k8s0*8;
    const us* b1p = Wt + (size_t)gb1*K + k8s1*8;

    const int nk = K >> 5;
    {
        us* b0 = SM;
        gload16(a0p, b0 + j0*8);
        gload16(a1p, b0 + j1*8);
        gload16(b0p, b0 + 4096 + j0*8);
        gload16(b1p, b0 + 4096 + j1*8);
        us* b1 = SM + 8192;
        gload16(a0p+32, b1 + j0*8);
        gload16(a1p+32, b1 + j1*8);
        gload16(b0p+32, b1 + 4096 + j0*8);
        gload16(b1p+32, b1 + 4096 + j1*8);
    }
    int cur = 0;
    for (int t=0; t<nk-1; ++t){
        asm volatile("s_waitcnt vmcnt(4)" ::: "memory");
        __builtin_amdgcn_s_barrier();
        __builtin_amdgcn_sched_barrier(0);
        const us* cbase = SM + cur*8192;
        gemm_compute(cbase, cbase+4096, wr, wc, lr, kg, acc);
        __builtin_amdgcn_sched_barrier(0);
        __builtin_amdgcn_s_barrier();
        if (t+2 < nk){
            us* nbase = SM + cur*8192;
            int k0 = (t+2)<<5;
            gload16(a0p+k0, nbase + j0*8);
            gload16(a1p+k0, nbase + j1*8);
            gload16(b0p+k0, nbase + 4096 + j0*8);
            gload16(b1p+k0, nbase + 4096 + j1*8);
        }
        cur ^= 1;
    }
    asm volatile("s_waitcnt vmcnt(0)" ::: "memory");
    __builtin_amdgcn_s_barrier();
    __builtin_amdgcn_sched_barrier(0);
    {
        const us* cbase = SM + cur*8192;
        gemm_compute(cbase, cbase+4096, wr, wc, lr, kg, acc);
    }
    __syncthreads();

    if (OBF && RIN==0){
        // ---- single-round bf16 epilogue: 128x128 us = 32KB, 1 barrier ----
        us* Cs16 = (us*)SM;
        #pragma unroll
        for (int mi=0;mi<4;mi++){
            #pragma unroll
            for (int ni=0;ni<4;ni++){
                #pragma unroll
                for (int r4=0;r4<4;r4++){
                    int row = wr*64 + mi*16 + kg*4 + r4;
                    int col = wc*64 + ni*16 + lr;
                    float v = acc[mi][ni][r4];
                    if (bias) v += bias[bn + col];
                    if (ACT==1) v = gelu_t(v);
                    int h = ((row>>2)&3) | ((row&1)<<2);
                    int punit = (col>>3) ^ h;
                    Cs16[row*128 + punit*8 + (col&7)] = f2bf(v);
                }
            }
        }
        __syncthreads();
        {
            int rbase = tid>>3, seg = tid&7;
            #pragma unroll
            for (int pass=0; pass<8; ++pass){
                int row = rbase + (pass>>1)*32;
                int half = pass&1;
                int grow = bm + row;
                if (grow < Mr){
                    int h = ((row>>2)&3) | ((row&1)<<2);
                    int punit = (half*8+seg) ^ h;
                    *(uint4*)((us*)Cout + (size_t)grow*N + bn + half*64 + seg*8)
                        = *(const uint4*)&Cs16[row*128 + punit*8];
                }
            }
        }
        return;
    }

    // ---- 2-round fp32 epilogue (RIN paths / fp32 out) ----
    float* Cs = (float*)SM;      // 64 x 128 f32 = 32KB
    #pragma unroll
    for (int er=0; er<2; er++){
        #pragma unroll
        for (int ml=0; ml<2; ml++){
            int mi = er*2 + ml;
            #pragma unroll
            for (int ni=0;ni<4;ni++){
                #pragma unroll
                for (int r4=0;r4<4;r4++){
                    int lrow = wr*32 + ml*16 + kg*4 + r4;
                    int lcol = wc*64 + ni*16 + lr;
                    int pcol = lcol ^ (((lrow>>2)&1)<<4);
                    float v = acc[mi][ni][r4];
                    if (bias) v += bias[bn + lcol];
                    if (ACT==1) v = gelu_t(v);
                    Cs[lrow*128 + pcol] = v;
                }
            }
        }
        __syncthreads();
        #pragma unroll
        for (int s=0; s<2; s++){
            int lrow = (tid>>3) + s*32;
            int tseg = tid&7;
            int pseg = tseg ^ ((lrow>>2)&1);
            const float4* src = (const float4*)&Cs[lrow*128 + pseg*16];
            float4 v0=src[0], v1=src[1], v2=src[2], v3=src[3];
            int grow = bm + (lrow>>5)*64 + (er*2 + ((lrow>>4)&1))*16 + (lrow&15);
            int gcol = bn + tseg*16;
            if (grow < Mr){
                if (RIN==1){
                    const float4* rp = (const float4*)((const float*)resid + (size_t)grow*N + gcol);
                    float4 r0=rp[0], r1=rp[1], r2=rp[2], r3=rp[3];
                    v0.x+=r0.x; v0.y+=r0.y; v0.z+=r0.z; v0.w+=r0.w;
                    v1.x+=r1.x; v1.y+=r1.y; v1.z+=r1.z; v1.w+=r1.w;
                    v2.x+=r2.x; v2.y+=r2.y; v2.z+=r2.z; v2.w+=r2.w;
                    v3.x+=r3.x; v3.y+=r3.y; v3.z+=r3.z; v3.w+=r3.w;
                } else if (RIN==2){
                    const uint4* rp = (const uint4*)((const us*)resid + (size_t)grow*N + gcol);
                    uint4 u0=rp[0], u1=rp[1];
                    v0.x+=bf2f((us)(u0.x&0xffff)); v0.y+=bf2f((us)(u0.x>>16));
                    v0.z+=bf2f((us)(u0.y&0xffff)); v0.w+=bf2f((us)(u0.y>>16));
                    v1.x+=bf2f((us)(u0.z&0xffff)); v1.y+=bf2f((us)(u0.z>>16));
                    v1.z+=bf2f((us)(u0.w&0xffff)); v1.w+=bf2f((us)(u0.w>>16));
                    v2.x+=bf2f((us)(u1.x&0xffff)); v2.y+=bf2f((us)(u1.x>>16));
                    v2.z+=bf2f((us)(u1.y&0xffff)); v2.w+=bf2f((us)(u1.y>>16));
                    v3.x+=bf2f((us)(u1.z&0xffff)); v3.y+=bf2f((us)(u1.z>>16));
                    v3.z+=bf2f((us)(u1.w&0xffff)); v3.w+=bf2f((us)(u1.w>>16));
                }
                if (OBF){
                    unsigned int w0 = (unsigned)f2bf(v0.x) | ((unsigned)f2bf(v0.y)<<16);
                    unsigned int w1 = (unsigned)f2bf(v0.z) | ((unsigned)f2bf(v0.w)<<16);
                    unsigned int w2 = (unsigned)f2bf(v1.x) | ((unsigned)f2bf(v1.y)<<16);
                    unsigned int w3 = (unsigned)f2bf(v1.z) | ((unsigned)f2bf(v1.w)<<16);
                    unsigned int w4 = (unsigned)f2bf(v2.x) | ((unsigned)f2bf(v2.y)<<16);
                    unsigned int w5 = (unsigned)f2bf(v2.z) | ((unsigned)f2bf(v2.w)<<16);
                    unsigned int w6 = (unsigned)f2bf(v3.x) | ((unsigned)f2bf(v3.y)<<16);
                    unsigned int w7 = (unsigned)f2bf(v3.z) | ((unsigned)f2bf(v3.w)<<16);
                    uint4* op = (uint4*)((us*)Cout + (size_t)grow*N + gcol);
                    uint4 u0; u0.x=w0; u0.y=w1; u0.z=w2; u0.w=w3;
                    uint4 u1; u1.x=w4; u1.y=w5; u1.z=w6; u1.w=w7;
                    op[0]=u0; op[1]=u1;
                } else {
                    float4* op = (float4*)((float*)Cout + (size_t)grow*N + gcol);
                    op[0]=v0; op[1]=v1; op[2]=v2; op[3]=v3;
                }
            }
        }
        __syncthreads();
    }
}

// ---------------- fp32 tiled GEMM (head only) ----------------
#define GBK 16
template<int ACT, bool RES>
__global__ void gemm_kernel(const float* __restrict__ A, const float* __restrict__ W,
                            const float* __restrict__ bias, const float* __restrict__ resid,
                            float* __restrict__ C, int N, int K, int KB){
    __shared__ float As[GBK][68];
    __shared__ float Ws[GBK][68];
    const int bm = blockIdx.y*64;
    const int bn = blockIdx.x*64;
    const int tid = threadIdx.x;
    const int tr = tid>>4, tc = tid&15;
    float acc[4][4] = {{0.f}};
    for (int k0 = 0; k0 < K; k0 += GBK){
        {
            int r = tid>>2;
            int c = (tid&3)<<2;
            int row = bm + r;
            float4 v = make_float4(0.f,0.f,0.f,0.f);
            if (row < N) v = *(const float4*)(A + (size_t)row*K + k0 + c);
            As[c+0][r]=v.x; As[c+1][r]=v.y; As[c+2][r]=v.z; As[c+3][r]=v.w;
        }
        {
            int r = tid>>4;
            int c = (tid&15)<<2;
            int col = bn + c;
            const float* wp = W + (size_t)(k0+r)*KB + col;
            float4 v;
            if ((KB & 3) == 0 && col + 3 < KB){
                v = *(const float4*)wp;
            } else {
                v.x = (col+0<KB)? wp[0]:0.f;
                v.y = (col+1<KB)? wp[1]:0.f;
                v.z = (col+2<KB)? wp[2]:0.f;
                v.w = (col+3<KB)? wp[3]:0.f;
            }
            *(float4*)(&Ws[r][c]) = v;
        }
        __syncthreads();
        #pragma unroll
        for (int kk=0;kk<GBK;kk++){
            const float4 av = *(const float4*)(&As[kk][tr<<2]);
            const float4 wv = *(const float4*)(&Ws[kk][tc<<2]);
            acc[0][0]+=av.x*wv.x; acc[0][1]+=av.x*wv.y; acc[0][2]+=av.x*wv.z; acc[0][3]+=av.x*wv.w;
            acc[1][0]+=av.y*wv.x; acc[1][1]+=av.y*wv.y; acc[1][2]+=av.y*wv.z; acc[1][3]+=av.y*wv.w;
            acc[2][0]+=av.z*wv.x; acc[2][1]+=av.z*wv.y; acc[2][2]+=av.z*wv.z; acc[2][3]+=av.z*wv.w;
            acc[3][0]+=av.w*wv.x; acc[3][1]+=av.w*wv.y; acc[3][2]+=av.w*wv.z; acc[3][3]+=av.w*wv.w;
        }
        __syncthreads();
    }
    #pragma unroll
    for (int ii=0;ii<4;ii++){
        int row = bm + (tr<<2) + ii;
        if (row >= N) continue;
        #pragma unroll
        for (int jj=0;jj<4;jj++){
            int col = bn + (tc<<2) + jj;
            if (col >= KB) continue;
            float v = acc[ii][jj];
            if (bias) v += bias[col];
            if (ACT==1) v = gelu_t(v);
            if (RES) v += resid[(size_t)row*KB + col];
            C[(size_t)row*KB + col] = v;
        }
    }
}

// ---------------- attention (bf16 in/out, fp32 math); wave-parallel softmax ----------------
__global__ void attn_kernel(const us* __restrict__ qkv, us* __restrict__ o){
    int bb = blockIdx.x >> 3;
    int h  = blockIdx.x & 7;
    __shared__ float qs[49][33], ks[49][33], vs[49][33];
    __shared__ float ss[49][49];
    const us* base = qkv + (size_t)bb*T_*768 + h*32;
    for (int i = threadIdx.x; i < 49*16; i += 256){
        int t = i>>4, d2 = i&15;
        unsigned int q = *(const unsigned int*)(base + (size_t)t*768 + d2*2);
        unsigned int k = *(const unsigned int*)(base + (size_t)t*768 + 256 + d2*2);
        unsigned int v = *(const unsigned int*)(base + (size_t)t*768 + 512 + d2*2);
        qs[t][d2*2] = bf2f((us)(q&0xffff)); qs[t][d2*2+1] = bf2f((us)(q>>16));
        ks[t][d2*2] = bf2f((us)(k&0xffff)); ks[t][d2*2+1] = bf2f((us)(k>>16));
        vs[t][d2*2] = bf2f((us)(v&0xffff)); vs[t][d2*2+1] = bf2f((us)(v>>16));
    }
    __syncthreads();
    for (int i = threadIdx.x; i < 49*49; i += 256){
        int r = i/49, c = i%49;
        float acc = 0.f;
        #pragma unroll
        for (int d=0;d<32;d++) acc += qs[r][d]*ks[c][d];
        ss[r][c] = acc*0.17677669529663687f;
    }
    __syncthreads();
    if (threadIdx.x < 196){
        int r = threadIdx.x>>2, q = threadIdx.x&3;
        float m = -1e30f;
        for (int c=q; c<49; c+=4) m = fmaxf(m, ss[r][c]);
        m = fmaxf(m, __shfl_xor(m,1,64)); m = fmaxf(m, __shfl_xor(m,2,64));
        float sum = 0.f;
        for (int c=q; c<49; c+=4){ float e = __expf(ss[r][c]-m); ss[r][c]=e; sum+=e; }
        sum += __shfl_xor(sum,1,64); sum += __shfl_xor(sum,2,64);
        float inv = __fdividef(1.0f, sum);
        for (int c=q; c<49; c+=4) ss[r][c] *= inv;
    }
    __syncthreads();
    for (int i = threadIdx.x; i < 49*32; i += 256){
        int r = i>>5, d = i&31;
        float acc = 0.f;
        for (int c=0;c<49;c++) acc += ss[r][c]*vs[c][d];
        o[((size_t)bb*T_ + r)*256 + h*32 + d] = f2bf(acc);
    }
}

// ---------------- score head (vectorized bf16 loads) ----------------
__global__ void score_kernel(const us* __restrict__ s2, const float* __restrict__ w3,
                             const float* __restrict__ b3, float* __restrict__ sc,
                             float* __restrict__ pred, int layer, int row0, int nrows){
    int lr = blockIdx.x*256 + threadIdx.x;
    if (lr >= nrows) return;
    int row = row0 + lr;
    int s = row / BT_;
    int r = row % BT_;
    int b = r / T_;
    int t = r % T_;
    const uint4* xv = (const uint4*)(s2 + (size_t)lr*128);
    float l0 = b3[0], l1 = b3[1];
    #pragma unroll
    for (int q=0;q<16;q++){
        uint4 u = xv[q];
        unsigned int uu[4] = {u.x,u.y,u.z,u.w};
        #pragma unroll
        for (int e=0;e<4;e++){
            float fa = bf2f((us)(uu[e]&0xffff));
            float fb = bf2f((us)(uu[e]>>16));
            int d = q*8 + e*2;
            l0 += fa*w3[d*2]     + fb*w3[(d+1)*2];
            l1 += fa*w3[d*2+1]   + fb*w3[(d+1)*2+1];
        }
    }
    float m = fmaxf(l0,l1);
    float e0 = __expf(l0-m), e1 = __expf(l1-m);
    float sc0 = __fdividef(e0, e0+e1);
    sc[b*(5*T_) + s*T_ + t] = sc0;
    pred[(size_t)b*(L_*5*T_) + (size_t)layer*(5*T_) + s*T_ + t] = sc0;
}

// ---------------- image fusion (both slots, in-place) ----------------
__global__ void img_fuse_kernel(float* __restrict__ X, const float* __restrict__ sc){
    size_t i = (size_t)blockIdx.x*256 + threadIdx.x;
    if (i >= (size_t)BT_*64) return;
    int row = (int)(i>>6), d4 = (int)(i&63);
    int b = row / T_, t = row % T_;
    float s0 = sc[b*(5*T_) + t];
    float s1 = sc[b*(5*T_) + T_ + t];
    float fm0  = (s0 > THRESH)? 1.f : 0.f;
    float fnm0 = -fm0 - 1.f;
    float fm1  = (s1 > THRESH)? 1.f : 0.f;
    float fnm1 = -fm1 - 1.f;
    float4* p0 = ((float4*)(X + (size_t)row*D_)) + d4;
    float4* p1 = ((float4*)(X + ((size_t)BT_ + row)*D_)) + d4;
    float4 a0 = *p0, a1 = *p1;
    float4 r0, r1;
    r0.x = a0.x*fm0 + a1.x*fnm0;  r0.y = a0.y*fm0 + a1.y*fnm0;
    r0.z = a0.z*fm0 + a1.z*fnm0;  r0.w = a0.w*fm0 + a1.w*fnm0;
    r1.x = a1.x*fm1 + a0.x*fnm1;  r1.y = a1.y*fm1 + a0.y*fnm1;
    r1.z = a1.z*fm1 + a0.z*fnm1;  r1.w = a1.w*fm1 + a0.w*fnm1;
    *p0 = r0; *p1 = r1;
}

// ---------------- point fusion: gather TWO rows of PM (MLP outputs) + fuse ----------------
// patch[k2][b,t] = PM[ b*T + idx[k2,0,b,t] ] + PM[ BT + b*T + idx[k2,1,b,t] ]
__global__ void pt_fuse_gather_kernel(float* __restrict__ X, const us* __restrict__ PM,
                                      const int* __restrict__ idx, const float* __restrict__ sc){
    size_t i = (size_t)blockIdx.x*256 + threadIdx.x;   // over 3*BT*64
    if (i >= (size_t)3*BT_*64) return;
    int vrow = (int)(i>>6), d4 = (int)(i&63);
    int k2 = vrow / BT_, grow = vrow % BT_;
    int b = grow / T_, t = grow % T_;
    float s = sc[b*(5*T_) + (2+k2)*T_ + t];
    float fm  = (s > THRESH)? 1.f : 0.f;
    float fnm = -fm - 1.f;
    int i0 = idx[(size_t)(k2*2+0)*BT_ + grow];
    int i1 = idx[(size_t)(k2*2+1)*BT_ + grow];
    uint2 u0 = ((const uint2*)(PM + ((size_t)b*T_ + i0)*D_))[d4];
    uint2 u1 = ((const uint2*)(PM + ((size_t)BT_ + (size_t)b*T_ + i1)*D_))[d4];
    float p0 = bf2f((us)(u0.x&0xffff)) + bf2f((us)(u1.x&0xffff));
    float p1 = bf2f((us)(u0.x>>16))    + bf2f((us)(u1.x>>16));
    float p2 = bf2f((us)(u0.y&0xffff)) + bf2f((us)(u1.y&0xffff));
    float p3 = bf2f((us)(u0.y>>16))    + bf2f((us)(u1.y>>16));
    float4* xp = ((float4*)(X + ((size_t)(2+k2)*BT_ + grow)*D_)) + d4;
    float4 a = *xp;
    float4 rr;
    rr.x = a.x*fm + p0*fnm;
    rr.y = a.y*fm + p1*fnm;
    rr.z = a.z*fm + p2*fnm;
    rr.w = a.w*fm + p3*fnm;
    *xp = rr;
}

// ---------------- max-pool over 245 tokens (float4 per thread) ----------------
__global__ void pool_kernel(const float* __restrict__ x, float* __restrict__ p){
    int i = blockIdx.x*256 + threadIdx.x;
    if (i >= B_*64) return;
    int b = i>>6, d4 = i&63;
    float4 m; m.x=m.y=m.z=m.w=-3.4e38f;
    for (int s=0;s<5;s++){
        const float4* bp = ((const float4*)(x + ((size_t)s*BT_ + (size_t)b*T_)*D_)) + d4;
        for (int t=0;t<T_;t++){
            float4 v = bp[(size_t)t*64];
            m.x=fmaxf(m.x,v.x); m.y=fmaxf(m.y,v.y); m.z=fmaxf(m.z,v.z); m.w=fmaxf(m.w,v.w);
        }
    }
    ((float4*)p)[i] = m;
}

static inline int cdiv(int a, int b){ return (a+b-1)/b; }

extern "C" void kernel_launch(void* const* d_in, const int* in_sizes, int n_in,
                              void* d_out, int out_size, void* d_ws, size_t ws_size,
                              hipStream_t stream)
{
    const float* in_img0 = (const float*)d_in[0];
    const float* in_img1 = (const float*)d_in[1];
    const float* in_p0   = (const float*)d_in[2];
    const float* in_p1   = (const float*)d_in[3];
    const float* in_p2   = (const float*)d_in[4];
    const int*   in_idx  = (const int*)d_in[5];
    const float* enc_ln1g = (const float*)d_in[6];
    const float* enc_ln1b = (const float*)d_in[7];
    const float* enc_wqkv = (const float*)d_in[8];
    const float* enc_wo   = (const float*)d_in[9];
    const float* enc_bo   = (const float*)d_in[10];
    const float* enc_ln2g = (const float*)d_in[11];
    const float* enc_ln2b = (const float*)d_in[12];
    const float* enc_w1   = (const float*)d_in[13];
    const float* enc_b1   = (const float*)d_in[14];
    const float* enc_w2   = (const float*)d_in[15];
    const float* enc_b2   = (const float*)d_in[16];
    const float* sc_lng   = (const float*)d_in[17];
    const float* sc_lnb   = (const float*)d_in[18];
    const float* sc_w1    = (const float*)d_in[19];
    const float* sc_b1    = (const float*)d_in[20];
    const float* sc_w2    = (const float*)d_in[21];
    const float* sc_b2    = (const float*)d_in[22];
    const float* sc_w3    = (const float*)d_in[23];
    const float* sc_b3    = (const float*)d_in[24];
    const float* pm_w1    = (const float*)d_in[25];
    const float* pm_b1    = (const float*)d_in[26];
    const float* pm_w2    = (const float*)d_in[27];
    const float* pm_b2    = (const float*)d_in[28];
    const float* pm_w3    = (const float*)d_in[29];
    const float* pm_b3    = (const float*)d_in[30];
    const float* hd_lng   = (const float*)d_in[31];
    const float* hd_lnb   = (const float*)d_in[32];
    const float* hd_w1    = (const float*)d_in[33];
    const float* hd_b1    = (const float*)d_in[34];
    const float* hd_w2    = (const float*)d_in[35];
    const float* hd_b2    = (const float*)d_in[36];

    // ---------------- workspace layout ----------------
    char* p = (char*)d_ws;
    float* X   = (float*)p;  p += (size_t)5*BT_*D_*4;
    float* SCb = (float*)p;  p += (size_t)B_*5*T_*4;
    us* PM   = (us*)p; p += (size_t)2*BT_*D_*2;          // patch-MLP outputs on image tokens
    us* WQKV = (us*)p; p += (size_t)8*768*256*2;
    us* WWO  = (us*)p; p += (size_t)8*256*256*2;
    us* WW1  = (us*)p; p += (size_t)8*1024*256*2;
    us* WW2  = (us*)p; p += (size_t)8*256*1024*2;
    us* WS1  = (us*)p; p += (size_t)4*256*256*2;
    us* WS2  = (us*)p; p += (size_t)4*128*256*2;
    us* WP1  = (us*)p; p += (size_t)4*1024*256*2;
    us* WP2  = (us*)p; p += (size_t)4*1024*1024*2;
    us* WP3  = (us*)p; p += (size_t)4*256*1024*2;
    float* POOL = (float*)p; p += (size_t)B_*256*4;
    float* HLN  = (float*)p; p += (size_t)B_*256*4;
    float* HMID = (float*)p; p += (size_t)B_*1024*4;
    size_t fixed = (size_t)(p - (char*)d_ws);
    long long pool = (long long)ws_size - (long long)fixed;
    if (pool < 0) pool = 0;
    // per-row scratch bytes: encoder 3072, score 1280, patch-MLP 4608
    auto chunkOf = [&](long long perRow, int maxRows)->int{
        long long c = pool / perRow;
        c = (c / T_) * T_;
        if (c < T_) c = T_;
        if (c > maxRows) c = maxRows;
        return (int)c;
    };
    int Cenc = chunkOf(3072, 3*BT_);
    int Csc  = chunkOf(1280, NTOK5);
    int Cpm  = chunkOf(4608, 2*BT_);
    char* pb = p;
    us* eR1 = (us*)pb;
    us* eR2 = (us*)(pb + (size_t)Cenc*512);
    us* eR3 = (us*)(pb + (size_t)Cenc*512 + (size_t)Cenc*2048);
    us* sR1 = (us*)pb;
    us* sS1 = (us*)(pb + (size_t)Csc*512);
    us* sS2 = (us*)(pb + (size_t)Csc*1024);
    us* cA  = (us*)pb;                                    // [Cpm,256]
    us* m1  = (us*)(pb + (size_t)Cpm*512);                // [Cpm,1024]
    us* m2  = (us*)(pb + (size_t)Cpm*512 + (size_t)Cpm*2048); // [Cpm,1024]

    float* out_smplx = (float*)d_out;
    float* out_pred  = out_smplx + (size_t)B_*OUT_;

    // ---------------- weight transpose + bf16 convert ----------------
    wtrans_kernel<<<dim3(cdiv(768,32), cdiv(256,32), 8),256,0,stream>>>(enc_wqkv, WQKV, 256, 768);
    wtrans_kernel<<<dim3(cdiv(256,32), cdiv(256,32), 8),256,0,stream>>>(enc_wo,   WWO,  256, 256);
    wtrans_kernel<<<dim3(cdiv(1024,32),cdiv(256,32), 8),256,0,stream>>>(enc_w1,   WW1,  256, 1024);
    wtrans_kernel<<<dim3(cdiv(256,32), cdiv(1024,32),8),256,0,stream>>>(enc_w2,   WW2,  1024,256);
    wtrans_kernel<<<dim3(cdiv(256,32), cdiv(256,32), 4),256,0,stream>>>(sc_w1,    WS1,  256, 256);
    wtrans_kernel<<<dim3(cdiv(128,32), cdiv(256,32), 4),256,0,stream>>>(sc_w2,    WS2,  256, 128);
    wtrans_kernel<<<dim3(cdiv(1024,32),cdiv(256,32), 4),256,0,stream>>>(pm_w1,    WP1,  256, 1024);
    wtrans_kernel<<<dim3(cdiv(1024,32),cdiv(1024,32),4),256,0,stream>>>(pm_w2,    WP2,  1024,1024);
    wtrans_kernel<<<dim3(cdiv(256,32), cdiv(1024,32),4),256,0,stream>>>(pm_w3,    WP3,  1024,256);

    copy_in_kernel<<<cdiv(NTOK5*64,256), 256, 0, stream>>>(in_img0,in_img1,in_p0,in_p1,in_p2, X);

    for (int i=0;i<L_;i++){
        // ---------- encoders ----------
        for (int grp=0; grp<2; grp++){
            int base  = (grp==0)? 0 : 2*BT_;
            int total = (grp==0)? 2*BT_ : 3*BT_;
            size_t wi = (size_t)(grp*L_ + i);
            for (int off=0; off<total; off+=Cenc){
                int R = total-off < Cenc ? total-off : Cenc;
                float* Xp = X + (size_t)(base+off)*D_;
                ln_kernel<true><<<cdiv(R,4),256,0,stream>>>(Xp, enc_ln1g+wi*D_, enc_ln1b+wi*D_, eR1, R);
                mfma_gemm<0,0,true><<<dim3(6, cdiv(R,128)),256,0,stream>>>(
                    eR1, WQKV + wi*768*256, nullptr, nullptr, eR2, R, 768, 256);
                attn_kernel<<<(R/T_)*8,256,0,stream>>>(eR2, eR3);
                mfma_gemm<0,1,false><<<dim3(2, cdiv(R,128)),256,0,stream>>>(
                    eR3, WWO + wi*256*256, enc_bo + wi*D_, Xp, Xp, R, 256, 256);
                ln_kernel<true><<<cdiv(R,4),256,0,stream>>>(Xp, enc_ln2g+wi*D_, enc_ln2b+wi*D_, eR1, R);
                mfma_gemm<1,0,true><<<dim3(8, cdiv(R,128)),256,0,stream>>>(
                    eR1, WW1 + wi*1024*256, enc_b1 + wi*M_, nullptr, eR2, R, 1024, 256);
                mfma_gemm<0,1,false><<<dim3(2, cdiv(R,128)),256,0,stream>>>(
                    eR2, WW2 + wi*256*1024, enc_b2 + wi*D_, Xp, Xp, R, 256, 1024);
            }
        }
        // ---------- score net ----------
        for (int off=0; off<NTOK5; off+=Csc){
            int R = NTOK5-off < Csc ? NTOK5-off : Csc;
            ln_kernel<true><<<cdiv(R,4),256,0,stream>>>(X + (size_t)off*D_,
                sc_lng+(size_t)i*D_, sc_lnb+(size_t)i*D_, sR1, R);
            mfma_gemm<1,0,true><<<dim3(2, cdiv(R,128)),256,0,stream>>>(
                sR1, WS1 + (size_t)i*256*256, sc_b1+(size_t)i*D_, nullptr, sS1, R, 256, 256);
            mfma_gemm<1,0,true><<<dim3(1, cdiv(R,128)),256,0,stream>>>(
                sS1, WS2 + (size_t)i*128*256, sc_b2+(size_t)i*128, nullptr, sS2, R, 128, 256);
            score_kernel<<<cdiv(R,256),256,0,stream>>>(
                sS2, sc_w3+(size_t)i*256, sc_b3+(size_t)i*2, SCb, out_pred, i, off, R);
        }
        // ---------- patch MLP on the 2BT IMAGE rows only (MLP∘gather = gather∘MLP) ----------
        for (int off=0; off<2*BT_; off+=Cpm){
            int R = 2*BT_-off < Cpm ? 2*BT_-off : Cpm;
            xcvt_kernel<<<cdiv(R*64,256),256,0,stream>>>(X + (size_t)off*D_, cA, R);
            mfma_gemm<1,0,true><<<dim3(8, cdiv(R,128)),256,0,stream>>>(
                cA, WP1 + (size_t)i*1024*256, pm_b1+(size_t)i*M_, nullptr, m1, R, 1024, 256);
            mfma_gemm<1,0,true><<<dim3(8, cdiv(R,128)),256,0,stream>>>(
                m1, WP2 + (size_t)i*1024*1024, pm_b2+(size_t)i*M_, nullptr, m2, R, 1024, 1024);
            mfma_gemm<0,0,true><<<dim3(2, cdiv(R,128)),256,0,stream>>>(
                m2, WP3 + (size_t)i*256*1024, pm_b3+(size_t)i*D_, nullptr, PM + (size_t)off*D_, R, 256, 1024);
        }
        // ---------- point fusion: gather MLP outputs + fuse (one dispatch) ----------
        pt_fuse_gather_kernel<<<cdiv(3*BT_*64,256),256,0,stream>>>(X, PM, in_idx, SCb);
        // ---------- image fusion LAST ----------
        img_fuse_kernel<<<cdiv(BT_*64,256),256,0,stream>>>(X, SCb);
    }
    // ---------- head (fp32) ----------
    pool_kernel<<<cdiv(B_*64,256),256,0,stream>>>(X, POOL);
    ln_kernel<false><<<cdiv(B_,4),256,0,stream>>>(POOL, hd_lng, hd_lnb, HLN, B_);
    gemm_kernel<1,false><<<dim3(16, cdiv(B_,64)),256,0,stream>>>(
        HLN, hd_w1, hd_b1, nullptr, HMID, B_, D_, M_);
    gemm_kernel<0,false><<<dim3(3, cdiv(B_,64)),256,0,stream>>>(
        HMID, hd_w2, hd_b2, nullptr, out_smplx, B_, M_, OUT_);
}

// Round 17
// 6693.005 us; speedup vs baseline: 1.6958x; 1.0130x over previous
//
#include <hip/hip_runtime.h>
#include <math.h>

#define B_ 512
#define T_ 49
#define D_ 256
#define M_ 1024
#define L_ 4
#define OUT_ 151
#define BT_ 25088            // B_*T_
#define NTOK5 (5*BT_)
#define THRESH 0.02f

typedef __bf16 bf16x8 __attribute__((ext_vector_type(8)));
typedef float f32x4 __attribute__((ext_vector_type(4)));
typedef unsigned short us;

__device__ __forceinline__ float gelu_t(float x){
    float u = 0.7978845608028654f * x * (1.0f + 0.044715f*x*x);
    float e = __expf(-2.0f*u);
    return __fdividef(x, 1.0f + e);
}
__device__ __forceinline__ us f2bf(float f){
    unsigned int u = __float_as_uint(f);
    u += 0x7fffu + ((u>>16)&1u);          // RNE
    return (us)(u>>16);
}
__device__ __forceinline__ float bf2f(us h){
    return __uint_as_float(((unsigned int)h)<<16);
}
__device__ __forceinline__ void gload16(const void* g, void* l){
    __builtin_amdgcn_global_load_lds(
        (const __attribute__((address_space(1))) void*)g,
        (__attribute__((address_space(3))) void*)l, 16, 0, 0);
}

// ---------------- copy 5 input streams into contiguous X buffer ----------------
__global__ void copy_in_kernel(const float* __restrict__ a0, const float* __restrict__ a1,
                               const float* __restrict__ a2, const float* __restrict__ a3,
                               const float* __restrict__ a4, float* __restrict__ dst){
    size_t i = (size_t)blockIdx.x*256 + threadIdx.x;
    if (i >= (size_t)NTOK5*64) return;
    int slot = (int)(i / ((size_t)BT_*64));
    size_t off = i % ((size_t)BT_*64);
    const float* src = slot==0?a0: slot==1?a1: slot==2?a2: slot==3?a3: a4;
    ((float4*)dst)[i] = ((const float4*)src)[off];
}

// ---------------- fp32 rows -> bf16 rows (patch-MLP input conversion) ----------------
__global__ void xcvt_kernel(const float* __restrict__ x, us* __restrict__ y, int nrows){
    size_t i = (size_t)blockIdx.x*256 + threadIdx.x;   // over nrows*64 float4s
    if (i >= (size_t)nrows*64) return;
    float4 v = ((const float4*)x)[i];
    ushort4 o; o.x=f2bf(v.x); o.y=f2bf(v.y); o.z=f2bf(v.z); o.w=f2bf(v.w);
    ((ushort4*)y)[i] = o;
}

// ---------------- LayerNorm D=256, 4 rows/block; OBF: bf16 or fp32 out ----------------
template<bool OBF>
__global__ void ln_kernel(const float* __restrict__ x, const float* __restrict__ g,
                          const float* __restrict__ b, void* __restrict__ y, int nrows){
    int row = blockIdx.x*4 + (threadIdx.x>>6);
    if (row >= nrows) return;
    int lane = threadIdx.x & 63;
    float4 v = ((const float4*)(x + (size_t)row*D_))[lane];
    float s  = v.x+v.y+v.z+v.w;
    float sq = v.x*v.x + v.y*v.y + v.z*v.z + v.w*v.w;
    #pragma unroll
    for (int o=32;o;o>>=1){ s += __shfl_xor(s,o,64); sq += __shfl_xor(sq,o,64); }
    float mu = s*(1.0f/256.0f);
    float rstd = rsqrtf(sq*(1.0f/256.0f) - mu*mu + 1e-5f);
    float4 gv = ((const float4*)g)[lane];
    float4 bv = ((const float4*)b)[lane];
    float o0 = (v.x-mu)*rstd*gv.x + bv.x;
    float o1 = (v.y-mu)*rstd*gv.y + bv.y;
    float o2 = (v.z-mu)*rstd*gv.z + bv.z;
    float o3 = (v.w-mu)*rstd*gv.w + bv.w;
    if (OBF){
        ushort4 o4; o4.x=f2bf(o0); o4.y=f2bf(o1); o4.z=f2bf(o2); o4.w=f2bf(o3);
        ((ushort4*)((us*)y + (size_t)row*D_))[lane] = o4;
    } else {
        float4 o4; o4.x=o0; o4.y=o1; o4.z=o2; o4.w=o3;
        ((float4*)((float*)y + (size_t)row*D_))[lane] = o4;
    }
}

// ---------------- weight transpose+convert: W[g][K][N] fp32 -> Wt[g][N][K] bf16 ----------------
__global__ void wtrans_kernel(const float* __restrict__ W, us* __restrict__ Wt,
                              int K, int N){
    int g = blockIdx.z;
    __shared__ float t[32][33];
    int k0 = blockIdx.y*32, n0 = blockIdx.x*32;
    int tx = threadIdx.x&31, ty = threadIdx.x>>5;
    for (int r=ty; r<32; r+=8){
        int k = k0+r, n = n0+tx;
        t[r][tx] = (k<K && n<N) ? W[(size_t)g*K*N + (size_t)k*N + n] : 0.f;
    }
    __syncthreads();
    for (int r=ty; r<32; r+=8){
        int n = n0+r, k = k0+tx;
        if (n<N && k<K) Wt[(size_t)g*N*K + (size_t)n*K + k] = f2bf(t[tx][r]);
    }
}

// ---------------- padded transpose: W[K][Nsrc] -> Wt[Ndst][K], rows >= Nsrc zeroed ----------------
__global__ void wtrans_pad_kernel(const float* __restrict__ W, us* __restrict__ Wt,
                                  int K, int Nsrc, int Ndst){
    __shared__ float t[32][33];
    int k0 = blockIdx.y*32, n0 = blockIdx.x*32;
    int tx = threadIdx.x&31, ty = threadIdx.x>>5;
    for (int r=ty; r<32; r+=8){
        int k = k0+r, n = n0+tx;
        t[r][tx] = (k<K && n<Nsrc) ? W[(size_t)k*Nsrc + n] : 0.f;
    }
    __syncthreads();
    for (int r=ty; r<32; r+=8){
        int n = n0+r, k = k0+tx;
        if (n<Ndst && k<K) Wt[(size_t)n*K + k] = f2bf(t[tx][r]);
    }
}

// ---------------- padded bias: o[0..Nsrc)=b, rest 0 ----------------
__global__ void padb_kernel(const float* __restrict__ b, float* __restrict__ o,
                            int Nsrc, int Ndst){
    int i = blockIdx.x*256 + threadIdx.x;
    if (i < Ndst) o[i] = (i < Nsrc) ? b[i] : 0.f;
}

// ---------------- head output copy: HOUT[512][256] -> out[512][151] ----------------
__global__ void headcopy_kernel(const float* __restrict__ src, float* __restrict__ dst){
    int i = blockIdx.x*256 + threadIdx.x;
    if (i >= B_*OUT_) return;
    int r = i / OUT_, c = i % OUT_;
    dst[i] = src[(size_t)r*256 + c];
}

__device__ __forceinline__ void gemm_compute(const us* As, const us* Bs,
        int wr, int wc, int lr, int kg, f32x4 (&acc)[4][4]){
    bf16x8 av[4], bv[4];
    #pragma unroll
    for (int mi=0;mi<4;mi++){
        int r = wr*64 + mi*16 + lr;
        av[mi] = *(const bf16x8*)(&As[r*32 + ((kg ^ ((r>>1)&3))<<3)]);
    }
    #pragma unroll
    for (int ni=0;ni<4;ni++){
        int c = wc*64 + ni*16 + lr;
        bv[ni] = *(const bf16x8*)(&Bs[c*32 + ((kg ^ ((c>>1)&3))<<3)]);
    }
    #pragma unroll
    for (int mi=0;mi<4;mi++)
        #pragma unroll
        for (int ni=0;ni<4;ni++)
            acc[mi][ni] = __builtin_amdgcn_mfma_f32_16x16x32_bf16(av[mi], bv[ni], acc[mi][ni], 0, 0, 0);
}

// ---------------- bf16 MFMA GEMM, 2-buf counted-vmcnt pipeline + XCD swizzle ----------------
// 128x128 tile, BK=32, 4 waves. RIN: 0 none, 1 fp32 resid, 2 bf16 resid (post-ACT).
// OBF && RIN==0: single-round bf16 LDS epilogue (1 barrier); else 2-round fp32.
template<int ACT, int RIN, bool OBF>
__global__ __launch_bounds__(256) void mfma_gemm(
    const us* __restrict__ A, const us* __restrict__ Wt,
    const float* __restrict__ bias, const void* __restrict__ resid,
    void* __restrict__ Cout, int Mr, int N, int K)
{
    __shared__ __align__(16) us SM[2*8192];            // 2 bufs x (A 8KB + B 8KB)
    const int nwg  = gridDim.x*gridDim.y;
    const int flat = blockIdx.y*gridDim.x + blockIdx.x;
    const int qq = nwg>>3, rr = nwg&7;
    const int xcd = flat&7, sidx = flat>>3;
    const int logical = (xcd<rr) ? (xcd*(qq+1)+sidx) : (rr*(qq+1)+(xcd-rr)*qq+sidx);
    const int bn = (logical % gridDim.x)*128;
    const int bm = (logical / gridDim.x)*128;
    const int tid = threadIdx.x;
    const int lane = tid&63, w = tid>>6;
    const int wr = w>>1, wc = w&1;
    const int lr = lane&15, kg = lane>>4;
    f32x4 acc[4][4] = {};

    const int j0 = tid, j1 = tid+256;
    const int row0 = j0>>2, row1 = j1>>2;
    const int k8s0 = (j0&3) ^ ((row0>>1)&3);
    const int k8s1 = (j1&3) ^ ((row1>>1)&3);
    int ga0 = bm+row0; if (ga0>=Mr) ga0=Mr-1;
    int ga1 = bm+row1; if (ga1>=Mr) ga1=Mr-1;
    int gb0 = bn+row0; if (gb0>=N) gb0=N-1;
    int gb1 = bn+row1; if (gb1>=N) gb1=N-1;
    const us* a0p = A  + (size_t)ga0*K + k8s0*8;
    const us* a1p = A  + (size_t)ga1*K + k8s1*8;
    const us* b0p = Wt + (size_t)gb0*K + k8s0*8;
    const us* b1p = Wt + (size_t)gb1*K + k8s1*8;

    const int nk = K >> 5;
    {
        us* b0 = SM;
        gload16(a0p, b0 + j0*8);
        gload16(a1p, b0 + j1*8);
        gload16(b0p, b0 + 4096 + j0*8);
        gload16(b1p, b0 + 4096 + j1*8);
        us* b1 = SM + 8192;
        gload16(a0p+32, b1 + j0*8);
        gload16(a1p+32, b1 + j1*8);
        gload16(b0p+32, b1 + 4096 + j0*8);
        gload16(b1p+32, b1 + 4096 + j1*8);
    }
    int cur = 0;
    for (int t=0; t<nk-1; ++t){
        asm volatile("s_waitcnt vmcnt(4)" ::: "memory");
        __builtin_amdgcn_s_barrier();
        __builtin_amdgcn_sched_barrier(0);
        const us* cbase = SM + cur*8192;
        gemm_compute(cbase, cbase+4096, wr, wc, lr, kg, acc);
        __builtin_amdgcn_sched_barrier(0);
        __builtin_amdgcn_s_barrier();
        if (t+2 < nk){
            us* nbase = SM + cur*8192;
            int k0 = (t+2)<<5;
            gload16(a0p+k0, nbase + j0*8);
            gload16(a1p+k0, nbase + j1*8);
            gload16(b0p+k0, nbase + 4096 + j0*8);
            gload16(b1p+k0, nbase + 4096 + j1*8);
        }
        cur ^= 1;
    }
    asm volatile("s_waitcnt vmcnt(0)" ::: "memory");
    __builtin_amdgcn_s_barrier();
    __builtin_amdgcn_sched_barrier(0);
    {
        const us* cbase = SM + cur*8192;
        gemm_compute(cbase, cbase+4096, wr, wc, lr, kg, acc);
    }
    __syncthreads();

    if (OBF && RIN==0){
        // ---- single-round bf16 epilogue: 128x128 us = 32KB, 1 barrier ----
        us* Cs16 = (us*)SM;
        #pragma unroll
        for (int mi=0;mi<4;mi++){
            #pragma unroll
            for (int ni=0;ni<4;ni++){
                #pragma unroll
                for (int r4=0;r4<4;r4++){
                    int row = wr*64 + mi*16 + kg*4 + r4;
                    int col = wc*64 + ni*16 + lr;
                    float v = acc[mi][ni][r4];
                    if (bias) v += bias[bn + col];
                    if (ACT==1) v = gelu_t(v);
                    int h = ((row>>2)&3) | ((row&1)<<2);
                    int punit = (col>>3) ^ h;
                    Cs16[row*128 + punit*8 + (col&7)] = f2bf(v);
                }
            }
        }
        __syncthreads();
        {
            int rbase = tid>>3, seg = tid&7;
            #pragma unroll
            for (int pass=0; pass<8; ++pass){
                int row = rbase + (pass>>1)*32;
                int half = pass&1;
                int grow = bm + row;
                if (grow < Mr){
                    int h = ((row>>2)&3) | ((row&1)<<2);
                    int punit = (half*8+seg) ^ h;
                    *(uint4*)((us*)Cout + (size_t)grow*N + bn + half*64 + seg*8)
                        = *(const uint4*)&Cs16[row*128 + punit*8];
                }
            }
        }
        return;
    }

    // ---- 2-round fp32 epilogue (RIN paths / fp32 out) ----
    float* Cs = (float*)SM;      // 64 x 128 f32 = 32KB
    #pragma unroll
    for (int er=0; er<2; er++){
        #pragma unroll
        for (int ml=0; ml<2; ml++){
            int mi = er*2 + ml;
            #pragma unroll
            for (int ni=0;ni<4;ni++){
                #pragma unroll
                for (int r4=0;r4<4;r4++){
                    int lrow = wr*32 + ml*16 + kg*4 + r4;
                    int lcol = wc*64 + ni*16 + lr;
                    int pcol = lcol ^ (((lrow>>2)&1)<<4);
                    float v = acc[mi][ni][r4];
                    if (bias) v += bias[bn + lcol];
                    if (ACT==1) v = gelu_t(v);
                    Cs[lrow*128 + pcol] = v;
                }
            }
        }
        __syncthreads();
        #pragma unroll
        for (int s=0; s<2; s++){
            int lrow = (tid>>3) + s*32;
            int tseg = tid&7;
            int pseg = tseg ^ ((lrow>>2)&1);
            const float4* src = (const float4*)&Cs[lrow*128 + pseg*16];
            float4 v0=src[0], v1=src[1], v2=src[2], v3=src[3];
            int grow = bm + (lrow>>5)*64 + (er*2 + ((lrow>>4)&1))*16 + (lrow&15);
            int gcol = bn + tseg*16;
            if (grow < Mr){
                if (RIN==1){
                    const float4* rp = (const float4*)((const float*)resid + (size_t)grow*N + gcol);
                    float4 r0=rp[0], r1=rp[1], r2=rp[2], r3=rp[3];
                    v0.x+=r0.x; v0.y+=r0.y; v0.z+=r0.z; v0.w+=r0.w;
                    v1.x+=r1.x; v1.y+=r1.y; v1.z+=r1.z; v1.w+=r1.w;
                    v2.x+=r2.x; v2.y+=r2.y; v2.z+=r2.z; v2.w+=r2.w;
                    v3.x+=r3.x; v3.y+=r3.y; v3.z+=r3.z; v3.w+=r3.w;
                } else if (RIN==2){
                    const uint4* rp = (const uint4*)((const us*)resid + (size_t)grow*N + gcol);
                    uint4 u0=rp[0], u1=rp[1];
                    v0.x+=bf2f((us)(u0.x&0xffff)); v0.y+=bf2f((us)(u0.x>>16));
                    v0.z+=bf2f((us)(u0.y&0xffff)); v0.w+=bf2f((us)(u0.y>>16));
                    v1.x+=bf2f((us)(u0.z&0xffff)); v1.y+=bf2f((us)(u0.z>>16));
                    v1.z+=bf2f((us)(u0.w&0xffff)); v1.w+=bf2f((us)(u0.w>>16));
                    v2.x+=bf2f((us)(u1.x&0xffff)); v2.y+=bf2f((us)(u1.x>>16));
                    v2.z+=bf2f((us)(u1.y&0xffff)); v2.w+=bf2f((us)(u1.y>>16));
                    v3.x+=bf2f((us)(u1.z&0xffff)); v3.y+=bf2f((us)(u1.z>>16));
                    v3.z+=bf2f((us)(u1.w&0xffff)); v3.w+=bf2f((us)(u1.w>>16));
                }
                if (OBF){
                    unsigned int w0 = (unsigned)f2bf(v0.x) | ((unsigned)f2bf(v0.y)<<16);
                    unsigned int w1 = (unsigned)f2bf(v0.z) | ((unsigned)f2bf(v0.w)<<16);
                    unsigned int w2 = (unsigned)f2bf(v1.x) | ((unsigned)f2bf(v1.y)<<16);
                    unsigned int w3 = (unsigned)f2bf(v1.z) | ((unsigned)f2bf(v1.w)<<16);
                    unsigned int w4 = (unsigned)f2bf(v2.x) | ((unsigned)f2bf(v2.y)<<16);
                    unsigned int w5 = (unsigned)f2bf(v2.z) | ((unsigned)f2bf(v2.w)<<16);
                    unsigned int w6 = (unsigned)f2bf(v3.x) | ((unsigned)f2bf(v3.y)<<16);
                    unsigned int w7 = (unsigned)f2bf(v3.z) | ((unsigned)f2bf(v3.w)<<16);
                    uint4* op = (uint4*)((us*)Cout + (size_t)grow*N + gcol);
                    uint4 u0; u0.x=w0; u0.y=w1; u0.z=w2; u0.w=w3;
                    uint4 u1; u1.x=w4; u1.y=w5; u1.z=w6; u1.w=w7;
                    op[0]=u0; op[1]=u1;
                } else {
                    float4* op = (float4*)((float*)Cout + (size_t)grow*N + gcol);
                    op[0]=v0; op[1]=v1; op[2]=v2; op[3]=v3;
                }
            }
        }
        __syncthreads();
    }
}

// ---------------- attention (bf16 in/out, fp32 math); wave-parallel softmax ----------------
__global__ void attn_kernel(const us* __restrict__ qkv, us* __restrict__ o){
    int bb = blockIdx.x >> 3;
    int h  = blockIdx.x & 7;
    __shared__ float qs[49][33], ks[49][33], vs[49][33];
    __shared__ float ss[49][49];
    const us* base = qkv + (size_t)bb*T_*768 + h*32;
    for (int i = threadIdx.x; i < 49*16; i += 256){
        int t = i>>4, d2 = i&15;
        unsigned int q = *(const unsigned int*)(base + (size_t)t*768 + d2*2);
        unsigned int k = *(const unsigned int*)(base + (size_t)t*768 + 256 + d2*2);
        unsigned int v = *(const unsigned int*)(base + (size_t)t*768 + 512 + d2*2);
        qs[t][d2*2] = bf2f((us)(q&0xffff)); qs[t][d2*2+1] = bf2f((us)(q>>16));
        ks[t][d2*2] = bf2f((us)(k&0xffff)); ks[t][d2*2+1] = bf2f((us)(k>>16));
        vs[t][d2*2] = bf2f((us)(v&0xffff)); vs[t][d2*2+1] = bf2f((us)(v>>16));
    }
    __syncthreads();
    for (int i = threadIdx.x; i < 49*49; i += 256){
        int r = i/49, c = i%49;
        float acc = 0.f;
        #pragma unroll
        for (int d=0;d<32;d++) acc += qs[r][d]*ks[c][d];
        ss[r][c] = acc*0.17677669529663687f;
    }
    __syncthreads();
    if (threadIdx.x < 196){
        int r = threadIdx.x>>2, q = threadIdx.x&3;
        float m = -1e30f;
        for (int c=q; c<49; c+=4) m = fmaxf(m, ss[r][c]);
        m = fmaxf(m, __shfl_xor(m,1,64)); m = fmaxf(m, __shfl_xor(m,2,64));
        float sum = 0.f;
        for (int c=q; c<49; c+=4){ float e = __expf(ss[r][c]-m); ss[r][c]=e; sum+=e; }
        sum += __shfl_xor(sum,1,64); sum += __shfl_xor(sum,2,64);
        float inv = __fdividef(1.0f, sum);
        for (int c=q; c<49; c+=4) ss[r][c] *= inv;
    }
    __syncthreads();
    for (int i = threadIdx.x; i < 49*32; i += 256){
        int r = i>>5, d = i&31;
        float acc = 0.f;
        for (int c=0;c<49;c++) acc += ss[r][c]*vs[c][d];
        o[((size_t)bb*T_ + r)*256 + h*32 + d] = f2bf(acc);
    }
}

// ---------------- score head (vectorized bf16 loads) ----------------
__global__ void score_kernel(const us* __restrict__ s2, const float* __restrict__ w3,
                             const float* __restrict__ b3, float* __restrict__ sc,
                             float* __restrict__ pred, int layer, int row0, int nrows){
    int lr = blockIdx.x*256 + threadIdx.x;
    if (lr >= nrows) return;
    int row = row0 + lr;
    int s = row / BT_;
    int r = row % BT_;
    int b = r / T_;
    int t = r % T_;
    const uint4* xv = (const uint4*)(s2 + (size_t)lr*128);
    float l0 = b3[0], l1 = b3[1];
    #pragma unroll
    for (int q=0;q<16;q++){
        uint4 u = xv[q];
        unsigned int uu[4] = {u.x,u.y,u.z,u.w};
        #pragma unroll
        for (int e=0;e<4;e++){
            float fa = bf2f((us)(uu[e]&0xffff));
            float fb = bf2f((us)(uu[e]>>16));
            int d = q*8 + e*2;
            l0 += fa*w3[d*2]     + fb*w3[(d+1)*2];
            l1 += fa*w3[d*2+1]   + fb*w3[(d+1)*2+1];
        }
    }
    float m = fmaxf(l0,l1);
    float e0 = __expf(l0-m), e1 = __expf(l1-m);
    float sc0 = __fdividef(e0, e0+e1);
    sc[b*(5*T_) + s*T_ + t] = sc0;
    pred[(size_t)b*(L_*5*T_) + (size_t)layer*(5*T_) + s*T_ + t] = sc0;
}

// ---------------- image fusion (both slots, in-place) ----------------
__global__ void img_fuse_kernel(float* __restrict__ X, const float* __restrict__ sc){
    size_t i = (size_t)blockIdx.x*256 + threadIdx.x;
    if (i >= (size_t)BT_*64) return;
    int row = (int)(i>>6), d4 = (int)(i&63);
    int b = row / T_, t = row % T_;
    float s0 = sc[b*(5*T_) + t];
    float s1 = sc[b*(5*T_) + T_ + t];
    float fm0  = (s0 > THRESH)? 1.f : 0.f;
    float fnm0 = -fm0 - 1.f;
    float fm1  = (s1 > THRESH)? 1.f : 0.f;
    float fnm1 = -fm1 - 1.f;
    float4* p0 = ((float4*)(X + (size_t)row*D_)) + d4;
    float4* p1 = ((float4*)(X + ((size_t)BT_ + row)*D_)) + d4;
    float4 a0 = *p0, a1 = *p1;
    float4 r0, r1;
    r0.x = a0.x*fm0 + a1.x*fnm0;  r0.y = a0.y*fm0 + a1.y*fnm0;
    r0.z = a0.z*fm0 + a1.z*fnm0;  r0.w = a0.w*fm0 + a1.w*fnm0;
    r1.x = a1.x*fm1 + a0.x*fnm1;  r1.y = a1.y*fm1 + a0.y*fnm1;
    r1.z = a1.z*fm1 + a0.z*fnm1;  r1.w = a1.w*fm1 + a0.w*fnm1;
    *p0 = r0; *p1 = r1;
}

// ---------------- point fusion: gather TWO rows of PM (MLP outputs) + fuse ----------------
__global__ void pt_fuse_gather_kernel(float* __restrict__ X, const us* __restrict__ PM,
                                      const int* __restrict__ idx, const float* __restrict__ sc){
    size_t i = (size_t)blockIdx.x*256 + threadIdx.x;   // over 3*BT*64
    if (i >= (size_t)3*BT_*64) return;
    int vrow = (int)(i>>6), d4 = (int)(i&63);
    int k2 = vrow / BT_, grow = vrow % BT_;
    int b = grow / T_, t = grow % T_;
    float s = sc[b*(5*T_) + (2+k2)*T_ + t];
    float fm  = (s > THRESH)? 1.f : 0.f;
    float fnm = -fm - 1.f;
    int i0 = idx[(size_t)(k2*2+0)*BT_ + grow];
    int i1 = idx[(size_t)(k2*2+1)*BT_ + grow];
    uint2 u0 = ((const uint2*)(PM + ((size_t)b*T_ + i0)*D_))[d4];
    uint2 u1 = ((const uint2*)(PM + ((size_t)BT_ + (size_t)b*T_ + i1)*D_))[d4];
    float p0 = bf2f((us)(u0.x&0xffff)) + bf2f((us)(u1.x&0xffff));
    float p1 = bf2f((us)(u0.x>>16))    + bf2f((us)(u1.x>>16));
    float p2 = bf2f((us)(u0.y&0xffff)) + bf2f((us)(u1.y&0xffff));
    float p3 = bf2f((us)(u0.y>>16))    + bf2f((us)(u1.y>>16));
    float4* xp = ((float4*)(X + ((size_t)(2+k2)*BT_ + grow)*D_)) + d4;
    float4 a = *xp;
    float4 rr;
    rr.x = a.x*fm + p0*fnm;
    rr.y = a.y*fm + p1*fnm;
    rr.z = a.z*fm + p2*fnm;
    rr.w = a.w*fm + p3*fnm;
    *xp = rr;
}

// ---------------- max-pool over 245 tokens (float4 per thread) ----------------
__global__ void pool_kernel(const float* __restrict__ x, float* __restrict__ p){
    int i = blockIdx.x*256 + threadIdx.x;
    if (i >= B_*64) return;
    int b = i>>6, d4 = i&63;
    float4 m; m.x=m.y=m.z=m.w=-3.4e38f;
    for (int s=0;s<5;s++){
        const float4* bp = ((const float4*)(x + ((size_t)s*BT_ + (size_t)b*T_)*D_)) + d4;
        for (int t=0;t<T_;t++){
            float4 v = bp[(size_t)t*64];
            m.x=fmaxf(m.x,v.x); m.y=fmaxf(m.y,v.y); m.z=fmaxf(m.z,v.z); m.w=fmaxf(m.w,v.w);
        }
    }
    ((float4*)p)[i] = m;
}

static inline int cdiv(int a, int b){ return (a+b-1)/b; }

extern "C" void kernel_launch(void* const* d_in, const int* in_sizes, int n_in,
                              void* d_out, int out_size, void* d_ws, size_t ws_size,
                              hipStream_t stream)
{
    const float* in_img0 = (const float*)d_in[0];
    const float* in_img1 = (const float*)d_in[1];
    const float* in_p0   = (const float*)d_in[2];
    const float* in_p1   = (const float*)d_in[3];
    const float* in_p2   = (const float*)d_in[4];
    const int*   in_idx  = (const int*)d_in[5];
    const float* enc_ln1g = (const float*)d_in[6];
    const float* enc_ln1b = (const float*)d_in[7];
    const float* enc_wqkv = (const float*)d_in[8];
    const float* enc_wo   = (const float*)d_in[9];
    const float* enc_bo   = (const float*)d_in[10];
    const float* enc_ln2g = (const float*)d_in[11];
    const float* enc_ln2b = (const float*)d_in[12];
    const float* enc_w1   = (const float*)d_in[13];
    const float* enc_b1   = (const float*)d_in[14];
    const float* enc_w2   = (const float*)d_in[15];
    const float* enc_b2   = (const float*)d_in[16];
    const float* sc_lng   = (const float*)d_in[17];
    const float* sc_lnb   = (const float*)d_in[18];
    const float* sc_w1    = (const float*)d_in[19];
    const float* sc_b1    = (const float*)d_in[20];
    const float* sc_w2    = (const float*)d_in[21];
    const float* sc_b2    = (const float*)d_in[22];
    const float* sc_w3    = (const float*)d_in[23];
    const float* sc_b3    = (const float*)d_in[24];
    const float* pm_w1    = (const float*)d_in[25];
    const float* pm_b1    = (const float*)d_in[26];
    const float* pm_w2    = (const float*)d_in[27];
    const float* pm_b2    = (const float*)d_in[28];
    const float* pm_w3    = (const float*)d_in[29];
    const float* pm_b3    = (const float*)d_in[30];
    const float* hd_lng   = (const float*)d_in[31];
    const float* hd_lnb   = (const float*)d_in[32];
    const float* hd_w1    = (const float*)d_in[33];
    const float* hd_b1    = (const float*)d_in[34];
    const float* hd_w2    = (const float*)d_in[35];
    const float* hd_b2    = (const float*)d_in[36];

    // ---------------- workspace layout ----------------
    char* p = (char*)d_ws;
    float* X   = (float*)p;  p += (size_t)5*BT_*D_*4;
    float* SCb = (float*)p;  p += (size_t)B_*5*T_*4;
    us* PM   = (us*)p; p += (size_t)2*BT_*D_*2;          // patch-MLP outputs on image tokens
    us* WQKV = (us*)p; p += (size_t)8*768*256*2;
    us* WWO  = (us*)p; p += (size_t)8*256*256*2;
    us* WW1  = (us*)p; p += (size_t)8*1024*256*2;
    us* WW2  = (us*)p; p += (size_t)8*256*1024*2;
    us* WS1  = (us*)p; p += (size_t)4*256*256*2;
    us* WS2  = (us*)p; p += (size_t)4*128*256*2;
    us* WP1  = (us*)p; p += (size_t)4*1024*256*2;
    us* WP2  = (us*)p; p += (size_t)4*1024*1024*2;
    us* WP3  = (us*)p; p += (size_t)4*256*1024*2;
    us* WH1  = (us*)p; p += (size_t)1024*256*2;          // head w1^T
    us* WH2  = (us*)p; p += (size_t)256*1024*2;          // head w2^T padded to 256 rows
    float* B2P  = (float*)p; p += (size_t)256*4;         // padded head bias2
    float* POOL = (float*)p; p += (size_t)B_*256*4;
    us*    HLNb = (us*)p;  p += (size_t)B_*256*2;
    us*    HMIDb= (us*)p;  p += (size_t)B_*1024*2;
    float* HOUT = (float*)p; p += (size_t)B_*256*4;
    size_t fixed = (size_t)(p - (char*)d_ws);
    long long pool = (long long)ws_size - (long long)fixed;
    if (pool < 0) pool = 0;
    // per-row scratch bytes: encoder 3072, score 1280, patch-MLP 4608
    auto chunkOf = [&](long long perRow, int maxRows)->int{
        long long c = pool / perRow;
        c = (c / T_) * T_;
        if (c < T_) c = T_;
        if (c > maxRows) c = maxRows;
        return (int)c;
    };
    int Cenc = chunkOf(3072, 3*BT_);
    int Csc  = chunkOf(1280, NTOK5);
    int Cpm  = chunkOf(4608, 2*BT_);
    char* pb = p;
    us* eR1 = (us*)pb;
    us* eR2 = (us*)(pb + (size_t)Cenc*512);
    us* eR3 = (us*)(pb + (size_t)Cenc*512 + (size_t)Cenc*2048);
    us* sR1 = (us*)pb;
    us* sS1 = (us*)(pb + (size_t)Csc*512);
    us* sS2 = (us*)(pb + (size_t)Csc*1024);
    us* cA  = (us*)pb;                                    // [Cpm,256]
    us* m1  = (us*)(pb + (size_t)Cpm*512);                // [Cpm,1024]
    us* m2  = (us*)(pb + (size_t)Cpm*512 + (size_t)Cpm*2048); // [Cpm,1024]

    float* out_smplx = (float*)d_out;
    float* out_pred  = out_smplx + (size_t)B_*OUT_;

    // ---------------- weight transpose + bf16 convert ----------------
    wtrans_kernel<<<dim3(cdiv(768,32), cdiv(256,32), 8),256,0,stream>>>(enc_wqkv, WQKV, 256, 768);
    wtrans_kernel<<<dim3(cdiv(256,32), cdiv(256,32), 8),256,0,stream>>>(enc_wo,   WWO,  256, 256);
    wtrans_kernel<<<dim3(cdiv(1024,32),cdiv(256,32), 8),256,0,stream>>>(enc_w1,   WW1,  256, 1024);
    wtrans_kernel<<<dim3(cdiv(256,32), cdiv(1024,32),8),256,0,stream>>>(enc_w2,   WW2,  1024,256);
    wtrans_kernel<<<dim3(cdiv(256,32), cdiv(256,32), 4),256,0,stream>>>(sc_w1,    WS1,  256, 256);
    wtrans_kernel<<<dim3(cdiv(128,32), cdiv(256,32), 4),256,0,stream>>>(sc_w2,    WS2,  256, 128);
    wtrans_kernel<<<dim3(cdiv(1024,32),cdiv(256,32), 4),256,0,stream>>>(pm_w1,    WP1,  256, 1024);
    wtrans_kernel<<<dim3(cdiv(1024,32),cdiv(1024,32),4),256,0,stream>>>(pm_w2,    WP2,  1024,1024);
    wtrans_kernel<<<dim3(cdiv(256,32), cdiv(1024,32),4),256,0,stream>>>(pm_w3,    WP3,  1024,256);
    wtrans_kernel<<<dim3(cdiv(1024,32),cdiv(256,32), 1),256,0,stream>>>(hd_w1,    WH1,  256, 1024);
    wtrans_pad_kernel<<<dim3(cdiv(256,32), cdiv(1024,32)),256,0,stream>>>(hd_w2, WH2, 1024, 151, 256);
    padb_kernel<<<1,256,0,stream>>>(hd_b2, B2P, 151, 256);

    copy_in_kernel<<<cdiv(NTOK5*64,256), 256, 0, stream>>>(in_img0,in_img1,in_p0,in_p1,in_p2, X);

    for (int i=0;i<L_;i++){
        // ---------- encoders ----------
        for (int grp=0; grp<2; grp++){
            int base  = (grp==0)? 0 : 2*BT_;
            int total = (grp==0)? 2*BT_ : 3*BT_;
            size_t wi = (size_t)(grp*L_ + i);
            for (int off=0; off<total; off+=Cenc){
                int R = total-off < Cenc ? total-off : Cenc;
                float* Xp = X + (size_t)(base+off)*D_;
                ln_kernel<true><<<cdiv(R,4),256,0,stream>>>(Xp, enc_ln1g+wi*D_, enc_ln1b+wi*D_, eR1, R);
                mfma_gemm<0,0,true><<<dim3(6, cdiv(R,128)),256,0,stream>>>(
                    eR1, WQKV + wi*768*256, nullptr, nullptr, eR2, R, 768, 256);
                attn_kernel<<<(R/T_)*8,256,0,stream>>>(eR2, eR3);
                mfma_gemm<0,1,false><<<dim3(2, cdiv(R,128)),256,0,stream>>>(
                    eR3, WWO + wi*256*256, enc_bo + wi*D_, Xp, Xp, R, 256, 256);
                ln_kernel<true><<<cdiv(R,4),256,0,stream>>>(Xp, enc_ln2g+wi*D_, enc_ln2b+wi*D_, eR1, R);
                mfma_gemm<1,0,true><<<dim3(8, cdiv(R,128)),256,0,stream>>>(
                    eR1, WW1 + wi*1024*256, enc_b1 + wi*M_, nullptr, eR2, R, 1024, 256);
                mfma_gemm<0,1,false><<<dim3(2, cdiv(R,128)),256,0,stream>>>(
                    eR2, WW2 + wi*256*1024, enc_b2 + wi*D_, Xp, Xp, R, 256, 1024);
            }
        }
        // ---------- score net ----------
        for (int off=0; off<NTOK5; off+=Csc){
            int R = NTOK5-off < Csc ? NTOK5-off : Csc;
            ln_kernel<true><<<cdiv(R,4),256,0,stream>>>(X + (size_t)off*D_,
                sc_lng+(size_t)i*D_, sc_lnb+(size_t)i*D_, sR1, R);
            mfma_gemm<1,0,true><<<dim3(2, cdiv(R,128)),256,0,stream>>>(
                sR1, WS1 + (size_t)i*256*256, sc_b1+(size_t)i*D_, nullptr, sS1, R, 256, 256);
            mfma_gemm<1,0,true><<<dim3(1, cdiv(R,128)),256,0,stream>>>(
                sS1, WS2 + (size_t)i*128*256, sc_b2+(size_t)i*128, nullptr, sS2, R, 128, 256);
            score_kernel<<<cdiv(R,256),256,0,stream>>>(
                sS2, sc_w3+(size_t)i*256, sc_b3+(size_t)i*2, SCb, out_pred, i, off, R);
        }
        // ---------- patch MLP on the 2BT IMAGE rows only (MLP∘gather = gather∘MLP) ----------
        for (int off=0; off<2*BT_; off+=Cpm){
            int R = 2*BT_-off < Cpm ? 2*BT_-off : Cpm;
            xcvt_kernel<<<cdiv(R*64,256),256,0,stream>>>(X + (size_t)off*D_, cA, R);
            mfma_gemm<1,0,true><<<dim3(8, cdiv(R,128)),256,0,stream>>>(
                cA, WP1 + (size_t)i*1024*256, pm_b1+(size_t)i*M_, nullptr, m1, R, 1024, 256);
            mfma_gemm<1,0,true><<<dim3(8, cdiv(R,128)),256,0,stream>>>(
                m1, WP2 + (size_t)i*1024*1024, pm_b2+(size_t)i*M_, nullptr, m2, R, 1024, 1024);
            mfma_gemm<0,0,true><<<dim3(2, cdiv(R,128)),256,0,stream>>>(
                m2, WP3 + (size_t)i*256*1024, pm_b3+(size_t)i*D_, nullptr, PM + (size_t)off*D_, R, 256, 1024);
        }
        // ---------- point fusion: gather MLP outputs + fuse (one dispatch) ----------
        pt_fuse_gather_kernel<<<cdiv(3*BT_*64,256),256,0,stream>>>(X, PM, in_idx, SCb);
        // ---------- image fusion LAST ----------
        img_fuse_kernel<<<cdiv(BT_*64,256),256,0,stream>>>(X, SCb);
    }
    // ---------- head (MFMA path; output padded to 256 cols then copied) ----------
    pool_kernel<<<cdiv(B_*64,256),256,0,stream>>>(X, POOL);
    ln_kernel<true><<<cdiv(B_,4),256,0,stream>>>(POOL, hd_lng, hd_lnb, HLNb, B_);
    mfma_gemm<1,0,true><<<dim3(8, cdiv(B_,128)),256,0,stream>>>(
        HLNb, WH1, hd_b1, nullptr, HMIDb, B_, 1024, 256);
    mfma_gemm<0,0,false><<<dim3(2, cdiv(B_,128)),256,0,stream>>>(
        HMIDb, WH2, B2P, nullptr, HOUT, B_, 256, 1024);
    headcopy_kernel<<<cdiv(B_*OUT_,256),256,0,stream>>>(HOUT, out_smplx);
}

// Round 18
// 6080.635 us; speedup vs baseline: 1.8666x; 1.1007x over previous
//
#include <hip/hip_runtime.h>
#include <math.h>

#define B_ 512
#define T_ 49
#define D_ 256
#define M_ 1024
#define L_ 4
#define OUT_ 151
#define BT_ 25088            // B_*T_
#define NTOK5 (5*BT_)
#define THRESH 0.02f

typedef __bf16 bf16x8 __attribute__((ext_vector_type(8)));
typedef float f32x4 __attribute__((ext_vector_type(4)));
typedef unsigned short us;

__device__ __forceinline__ float gelu_t(float x){
    float u = 0.7978845608028654f * x * (1.0f + 0.044715f*x*x);
    float e = __expf(-2.0f*u);
    return __fdividef(x, 1.0f + e);
}
__device__ __forceinline__ us f2bf(float f){
    unsigned int u = __float_as_uint(f);
    u += 0x7fffu + ((u>>16)&1u);          // RNE
    return (us)(u>>16);
}
__device__ __forceinline__ float bf2f(us h){
    return __uint_as_float(((unsigned int)h)<<16);
}
__device__ __forceinline__ void gload16(const void* g, void* l){
    __builtin_amdgcn_global_load_lds(
        (const __attribute__((address_space(1))) void*)g,
        (__attribute__((address_space(3))) void*)l, 16, 0, 0);
}

// ---------------- copy 5 input streams into contiguous X buffer ----------------
__global__ void copy_in_kernel(const float* __restrict__ a0, const float* __restrict__ a1,
                               const float* __restrict__ a2, const float* __restrict__ a3,
                               const float* __restrict__ a4, float* __restrict__ dst){
    size_t i = (size_t)blockIdx.x*256 + threadIdx.x;
    if (i >= (size_t)NTOK5*64) return;
    int slot = (int)(i / ((size_t)BT_*64));
    size_t off = i % ((size_t)BT_*64);
    const float* src = slot==0?a0: slot==1?a1: slot==2?a2: slot==3?a3: a4;
    ((float4*)dst)[i] = ((const float4*)src)[off];
}

// ---------------- fp32 rows -> bf16 rows ----------------
__global__ void xcvt_kernel(const float* __restrict__ x, us* __restrict__ y, int nrows){
    size_t i = (size_t)blockIdx.x*256 + threadIdx.x;
    if (i >= (size_t)nrows*64) return;
    float4 v = ((const float4*)x)[i];
    ushort4 o; o.x=f2bf(v.x); o.y=f2bf(v.y); o.z=f2bf(v.z); o.w=f2bf(v.w);
    ((ushort4*)y)[i] = o;
}

// ---------------- LayerNorm D=256, 4 rows/block; OBF: bf16 or fp32 out ----------------
template<bool OBF>
__global__ void ln_kernel(const float* __restrict__ x, const float* __restrict__ g,
                          const float* __restrict__ b, void* __restrict__ y, int nrows){
    int row = blockIdx.x*4 + (threadIdx.x>>6);
    if (row >= nrows) return;
    int lane = threadIdx.x & 63;
    float4 v = ((const float4*)(x + (size_t)row*D_))[lane];
    float s  = v.x+v.y+v.z+v.w;
    float sq = v.x*v.x + v.y*v.y + v.z*v.z + v.w*v.w;
    #pragma unroll
    for (int o=32;o;o>>=1){ s += __shfl_xor(s,o,64); sq += __shfl_xor(sq,o,64); }
    float mu = s*(1.0f/256.0f);
    float rstd = rsqrtf(sq*(1.0f/256.0f) - mu*mu + 1e-5f);
    float4 gv = ((const float4*)g)[lane];
    float4 bv = ((const float4*)b)[lane];
    float o0 = (v.x-mu)*rstd*gv.x + bv.x;
    float o1 = (v.y-mu)*rstd*gv.y + bv.y;
    float o2 = (v.z-mu)*rstd*gv.z + bv.z;
    float o3 = (v.w-mu)*rstd*gv.w + bv.w;
    if (OBF){
        ushort4 o4; o4.x=f2bf(o0); o4.y=f2bf(o1); o4.z=f2bf(o2); o4.w=f2bf(o3);
        ((ushort4*)((us*)y + (size_t)row*D_))[lane] = o4;
    } else {
        float4 o4; o4.x=o0; o4.y=o1; o4.z=o2; o4.w=o3;
        ((float4*)((float*)y + (size_t)row*D_))[lane] = o4;
    }
}

// ---------------- weight transpose+convert: W[g][K][N] fp32 -> Wt[g][N][K] bf16 ----------------
__global__ void wtrans_kernel(const float* __restrict__ W, us* __restrict__ Wt,
                              int K, int N){
    int g = blockIdx.z;
    __shared__ float t[32][33];
    int k0 = blockIdx.y*32, n0 = blockIdx.x*32;
    int tx = threadIdx.x&31, ty = threadIdx.x>>5;
    for (int r=ty; r<32; r+=8){
        int k = k0+r, n = n0+tx;
        t[r][tx] = (k<K && n<N) ? W[(size_t)g*K*N + (size_t)k*N + n] : 0.f;
    }
    __syncthreads();
    for (int r=ty; r<32; r+=8){
        int n = n0+r, k = k0+tx;
        if (n<N && k<K) Wt[(size_t)g*N*K + (size_t)n*K + k] = f2bf(t[tx][r]);
    }
}

// ---------------- padded transpose: W[K][Nsrc] -> Wt[Ndst][K], rows >= Nsrc zeroed ----------------
__global__ void wtrans_pad_kernel(const float* __restrict__ W, us* __restrict__ Wt,
                                  int K, int Nsrc, int Ndst){
    __shared__ float t[32][33];
    int k0 = blockIdx.y*32, n0 = blockIdx.x*32;
    int tx = threadIdx.x&31, ty = threadIdx.x>>5;
    for (int r=ty; r<32; r+=8){
        int k = k0+r, n = n0+tx;
        t[r][tx] = (k<K && n<Nsrc) ? W[(size_t)k*Nsrc + n] : 0.f;
    }
    __syncthreads();
    for (int r=ty; r<32; r+=8){
        int n = n0+r, k = k0+tx;
        if (n<Ndst && k<K) Wt[(size_t)n*K + k] = f2bf(t[tx][r]);
    }
}

// ---------------- padded bias ----------------
__global__ void padb_kernel(const float* __restrict__ b, float* __restrict__ o,
                            int Nsrc, int Ndst){
    int i = blockIdx.x*256 + threadIdx.x;
    if (i < Ndst) o[i] = (i < Nsrc) ? b[i] : 0.f;
}

// ---------------- head output copy ----------------
__global__ void headcopy_kernel(const float* __restrict__ src, float* __restrict__ dst){
    int i = blockIdx.x*256 + threadIdx.x;
    if (i >= B_*OUT_) return;
    int r = i / OUT_, c = i % OUT_;
    dst[i] = src[(size_t)r*256 + c];
}

__device__ __forceinline__ void gemm_compute(const us* As, const us* Bs,
        int wr, int wc, int lr, int kg, f32x4 (&acc)[4][4]){
    bf16x8 av[4], bv[4];
    #pragma unroll
    for (int mi=0;mi<4;mi++){
        int r = wr*64 + mi*16 + lr;
        av[mi] = *(const bf16x8*)(&As[r*32 + ((kg ^ ((r>>1)&3))<<3)]);
    }
    #pragma unroll
    for (int ni=0;ni<4;ni++){
        int c = wc*64 + ni*16 + lr;
        bv[ni] = *(const bf16x8*)(&Bs[c*32 + ((kg ^ ((c>>1)&3))<<3)]);
    }
    #pragma unroll
    for (int mi=0;mi<4;mi++)
        #pragma unroll
        for (int ni=0;ni<4;ni++)
            acc[mi][ni] = __builtin_amdgcn_mfma_f32_16x16x32_bf16(av[mi], bv[ni], acc[mi][ni], 0, 0, 0);
}

// ---------------- bf16 MFMA GEMM, 2-buf counted-vmcnt pipeline + XCD swizzle ----------------
template<int ACT, int RIN, bool OBF>
__global__ __launch_bounds__(256) void mfma_gemm(
    const us* __restrict__ A, const us* __restrict__ Wt,
    const float* __restrict__ bias, const void* __restrict__ resid,
    void* __restrict__ Cout, int Mr, int N, int K)
{
    __shared__ __align__(16) us SM[2*8192];
    const int nwg  = gridDim.x*gridDim.y;
    const int flat = blockIdx.y*gridDim.x + blockIdx.x;
    const int qq = nwg>>3, rr = nwg&7;
    const int xcd = flat&7, sidx = flat>>3;
    const int logical = (xcd<rr) ? (xcd*(qq+1)+sidx) : (rr*(qq+1)+(xcd-rr)*qq+sidx);
    const int bn = (logical % gridDim.x)*128;
    const int bm = (logical / gridDim.x)*128;
    const int tid = threadIdx.x;
    const int lane = tid&63, w = tid>>6;
    const int wr = w>>1, wc = w&1;
    const int lr = lane&15, kg = lane>>4;
    f32x4 acc[4][4] = {};

    const int j0 = tid, j1 = tid+256;
    const int row0 = j0>>2, row1 = j1>>2;
    const int k8s0 = (j0&3) ^ ((row0>>1)&3);
    const int k8s1 = (j1&3) ^ ((row1>>1)&3);
    int ga0 = bm+row0; if (ga0>=Mr) ga0=Mr-1;
    int ga1 = bm+row1; if (ga1>=Mr) ga1=Mr-1;
    int gb0 = bn+row0; if (gb0>=N) gb0=N-1;
    int gb1 = bn+row1; if (gb1>=N) gb1=N-1;
    const us* a0p = A  + (size_t)ga0*K + k8s0*8;
    const us* a1p = A  + (size_t)ga1*K + k8s1*8;
    const us* b0p = Wt + (size_t)gb0*K + k8s0*8;
    const us* b1p = Wt + (size_t)gb1*K + k8s1*8;

    const int nk = K >> 5;
    {
        us* b0 = SM;
        gload16(a0p, b0 + j0*8);
        gload16(a1p, b0 + j1*8);
        gload16(b0p, b0 + 4096 + j0*8);
        gload16(b1p, b0 + 4096 + j1*8);
        us* b1 = SM + 8192;
        gload16(a0p+32, b1 + j0*8);
        gload16(a1p+32, b1 + j1*8);
        gload16(b0p+32, b1 + 4096 + j0*8);
        gload16(b1p+32, b1 + 4096 + j1*8);
    }
    int cur = 0;
    for (int t=0; t<nk-1; ++t){
        asm volatile("s_waitcnt vmcnt(4)" ::: "memory");
        __builtin_amdgcn_s_barrier();
        __builtin_amdgcn_sched_barrier(0);
        const us* cbase = SM + cur*8192;
        gemm_compute(cbase, cbase+4096, wr, wc, lr, kg, acc);
        __builtin_amdgcn_sched_barrier(0);
        __builtin_amdgcn_s_barrier();
        if (t+2 < nk){
            us* nbase = SM + cur*8192;
            int k0 = (t+2)<<5;
            gload16(a0p+k0, nbase + j0*8);
            gload16(a1p+k0, nbase + j1*8);
            gload16(b0p+k0, nbase + 4096 + j0*8);
            gload16(b1p+k0, nbase + 4096 + j1*8);
        }
        cur ^= 1;
    }
    asm volatile("s_waitcnt vmcnt(0)" ::: "memory");
    __builtin_amdgcn_s_barrier();
    __builtin_amdgcn_sched_barrier(0);
    {
        const us* cbase = SM + cur*8192;
        gemm_compute(cbase, cbase+4096, wr, wc, lr, kg, acc);
    }
    __syncthreads();

    if (OBF && RIN==0){
        us* Cs16 = (us*)SM;
        #pragma unroll
        for (int mi=0;mi<4;mi++){
            #pragma unroll
            for (int ni=0;ni<4;ni++){
                #pragma unroll
                for (int r4=0;r4<4;r4++){
                    int row = wr*64 + mi*16 + kg*4 + r4;
                    int col = wc*64 + ni*16 + lr;
                    float v = acc[mi][ni][r4];
                    if (bias) v += bias[bn + col];
                    if (ACT==1) v = gelu_t(v);
                    int h = ((row>>2)&3) | ((row&1)<<2);
                    int punit = (col>>3) ^ h;
                    Cs16[row*128 + punit*8 + (col&7)] = f2bf(v);
                }
            }
        }
        __syncthreads();
        {
            int rbase = tid>>3, seg = tid&7;
            #pragma unroll
            for (int pass=0; pass<8; ++pass){
                int row = rbase + (pass>>1)*32;
                int half = pass&1;
                int grow = bm + row;
                if (grow < Mr){
                    int h = ((row>>2)&3) | ((row&1)<<2);
                    int punit = (half*8+seg) ^ h;
                    *(uint4*)((us*)Cout + (size_t)grow*N + bn + half*64 + seg*8)
                        = *(const uint4*)&Cs16[row*128 + punit*8];
                }
            }
        }
        return;
    }

    float* Cs = (float*)SM;
    #pragma unroll
    for (int er=0; er<2; er++){
        #pragma unroll
        for (int ml=0; ml<2; ml++){
            int mi = er*2 + ml;
            #pragma unroll
            for (int ni=0;ni<4;ni++){
                #pragma unroll
                for (int r4=0;r4<4;r4++){
                    int lrow = wr*32 + ml*16 + kg*4 + r4;
                    int lcol = wc*64 + ni*16 + lr;
                    int pcol = lcol ^ (((lrow>>2)&1)<<4);
                    float v = acc[mi][ni][r4];
                    if (bias) v += bias[bn + lcol];
                    if (ACT==1) v = gelu_t(v);
                    Cs[lrow*128 + pcol] = v;
                }
            }
        }
        __syncthreads();
        #pragma unroll
        for (int s=0; s<2; s++){
            int lrow = (tid>>3) + s*32;
            int tseg = tid&7;
            int pseg = tseg ^ ((lrow>>2)&1);
            const float4* src = (const float4*)&Cs[lrow*128 + pseg*16];
            float4 v0=src[0], v1=src[1], v2=src[2], v3=src[3];
            int grow = bm + (lrow>>5)*64 + (er*2 + ((lrow>>4)&1))*16 + (lrow&15);
            int gcol = bn + tseg*16;
            if (grow < Mr){
                if (RIN==1){
                    const float4* rp = (const float4*)((const float*)resid + (size_t)grow*N + gcol);
                    float4 r0=rp[0], r1=rp[1], r2=rp[2], r3=rp[3];
                    v0.x+=r0.x; v0.y+=r0.y; v0.z+=r0.z; v0.w+=r0.w;
                    v1.x+=r1.x; v1.y+=r1.y; v1.z+=r1.z; v1.w+=r1.w;
                    v2.x+=r2.x; v2.y+=r2.y; v2.z+=r2.z; v2.w+=r2.w;
                    v3.x+=r3.x; v3.y+=r3.y; v3.z+=r3.z; v3.w+=r3.w;
                } else if (RIN==2){
                    const uint4* rp = (const uint4*)((const us*)resid + (size_t)grow*N + gcol);
                    uint4 u0=rp[0], u1=rp[1];
                    v0.x+=bf2f((us)(u0.x&0xffff)); v0.y+=bf2f((us)(u0.x>>16));
                    v0.z+=bf2f((us)(u0.y&0xffff)); v0.w+=bf2f((us)(u0.y>>16));
                    v1.x+=bf2f((us)(u0.z&0xffff)); v1.y+=bf2f((us)(u0.z>>16));
                    v1.z+=bf2f((us)(u0.w&0xffff)); v1.w+=bf2f((us)(u0.w>>16));
                    v2.x+=bf2f((us)(u1.x&0xffff)); v2.y+=bf2f((us)(u1.x>>16));
                    v2.z+=bf2f((us)(u1.y&0xffff)); v2.w+=bf2f((us)(u1.y>>16));
                    v3.x+=bf2f((us)(u1.z&0xffff)); v3.y+=bf2f((us)(u1.z>>16));
                    v3.z+=bf2f((us)(u1.w&0xffff)); v3.w+=bf2f((us)(u1.w>>16));
                }
                if (OBF){
                    unsigned int w0 = (unsigned)f2bf(v0.x) | ((unsigned)f2bf(v0.y)<<16);
                    unsigned int w1 = (unsigned)f2bf(v0.z) | ((unsigned)f2bf(v0.w)<<16);
                    unsigned int w2 = (unsigned)f2bf(v1.x) | ((unsigned)f2bf(v1.y)<<16);
                    unsigned int w3 = (unsigned)f2bf(v1.z) | ((unsigned)f2bf(v1.w)<<16);
                    unsigned int w4 = (unsigned)f2bf(v2.x) | ((unsigned)f2bf(v2.y)<<16);
                    unsigned int w5 = (unsigned)f2bf(v2.z) | ((unsigned)f2bf(v2.w)<<16);
                    unsigned int w6 = (unsigned)f2bf(v3.x) | ((unsigned)f2bf(v3.y)<<16);
                    unsigned int w7 = (unsigned)f2bf(v3.z) | ((unsigned)f2bf(v3.w)<<16);
                    uint4* op = (uint4*)((us*)Cout + (size_t)grow*N + gcol);
                    uint4 u0; u0.x=w0; u0.y=w1; u0.z=w2; u0.w=w3;
                    uint4 u1; u1.x=w4; u1.y=w5; u1.z=w6; u1.w=w7;
                    op[0]=u0; op[1]=u1;
                } else {
                    float4* op = (float4*)((float*)Cout + (size_t)grow*N + gcol);
                    op[0]=v0; op[1]=v1; op[2]=v2; op[3]=v3;
                }
            }
        }
        __syncthreads();
    }
}

// ---------------- attention: thread-per-row, registers for Q/S/O, broadcast K/V ----------------
// 2 waves/block, one (b,h) per wave. Softmax fully thread-local (S row in regs).
// K/V staged f32 in LDS [49][36] (16B-aligned rows); all inner reads wave-uniform
// (broadcast -> bank-conflict impossible).
__global__ __launch_bounds__(128) void attn_kernel(const us* __restrict__ qkv,
                                                   us* __restrict__ o){
    __shared__ float ks[2][T_][36], vs[2][T_][36];
    const int w = threadIdx.x >> 6, lane = threadIdx.x & 63;
    const int bh = blockIdx.x*2 + w;
    const int bb = bh >> 3, h = bh & 7;
    const us* base = qkv + (size_t)bb*T_*768 + h*32;
    if (lane < T_){
        const uint4* kp = (const uint4*)(base + (size_t)lane*768 + 256);
        const uint4* vp = (const uint4*)(base + (size_t)lane*768 + 512);
        #pragma unroll
        for (int j=0;j<4;j++){
            uint4 ku = kp[j], vu = vp[j];
            unsigned ka[4]={ku.x,ku.y,ku.z,ku.w}, va[4]={vu.x,vu.y,vu.z,vu.w};
            #pragma unroll
            for (int e=0;e<4;e++){
                ks[w][lane][j*8+e*2]   = bf2f((us)(ka[e]&0xffffu));
                ks[w][lane][j*8+e*2+1] = bf2f((us)(ka[e]>>16));
                vs[w][lane][j*8+e*2]   = bf2f((us)(va[e]&0xffffu));
                vs[w][lane][j*8+e*2+1] = bf2f((us)(va[e]>>16));
            }
        }
    }
    __syncthreads();
    if (lane >= T_) return;
    float q[32];
    {
        const uint4* qp = (const uint4*)(base + (size_t)lane*768);
        #pragma unroll
        for (int j=0;j<4;j++){
            uint4 qu = qp[j];
            unsigned qa[4]={qu.x,qu.y,qu.z,qu.w};
            #pragma unroll
            for (int e=0;e<4;e++){
                q[j*8+e*2]   = bf2f((us)(qa[e]&0xffffu));
                q[j*8+e*2+1] = bf2f((us)(qa[e]>>16));
            }
        }
    }
    float S[T_];
    #pragma unroll
    for (int c=0;c<T_;c++){
        float acc = 0.f;
        #pragma unroll
        for (int d=0;d<32;d++) acc += q[d]*ks[w][c][d];
        S[c] = acc*0.17677669529663687f;
    }
    float m = S[0];
    #pragma unroll
    for (int c=1;c<T_;c++) m = fmaxf(m, S[c]);
    float sum = 0.f;
    #pragma unroll
    for (int c=0;c<T_;c++){ S[c] = __expf(S[c]-m); sum += S[c]; }
    float inv = __fdividef(1.f, sum);
    float oa[32];
    #pragma unroll
    for (int d=0;d<32;d++) oa[d] = 0.f;
    #pragma unroll
    for (int c=0;c<T_;c++){
        float p2 = S[c]*inv;
        #pragma unroll
        for (int d=0;d<32;d++) oa[d] += p2*vs[w][c][d];
    }
    unsigned* op = (unsigned*)(o + ((size_t)bb*T_ + lane)*256 + h*32);
    #pragma unroll
    for (int j=0;j<16;j++)
        op[j] = (unsigned)f2bf(oa[2*j]) | ((unsigned)f2bf(oa[2*j+1])<<16);
}

// ---------------- score head (vectorized bf16 loads) ----------------
__global__ void score_kernel(const us* __restrict__ s2, const float* __restrict__ w3,
                             const float* __restrict__ b3, float* __restrict__ sc,
                             float* __restrict__ pred, int layer, int row0, int nrows){
    int lr = blockIdx.x*256 + threadIdx.x;
    if (lr >= nrows) return;
    int row = row0 + lr;
    int s = row / BT_;
    int r = row % BT_;
    int b = r / T_;
    int t = r % T_;
    const uint4* xv = (const uint4*)(s2 + (size_t)lr*128);
    float l0 = b3[0], l1 = b3[1];
    #pragma unroll
    for (int q=0;q<16;q++){
        uint4 u = xv[q];
        unsigned int uu[4] = {u.x,u.y,u.z,u.w};
        #pragma unroll
        for (int e=0;e<4;e++){
            float fa = bf2f((us)(uu[e]&0xffff));
            float fb = bf2f((us)(uu[e]>>16));
            int d = q*8 + e*2;
            l0 += fa*w3[d*2]     + fb*w3[(d+1)*2];
            l1 += fa*w3[d*2+1]   + fb*w3[(d+1)*2+1];
        }
    }
    float m = fmaxf(l0,l1);
    float e0 = __expf(l0-m), e1 = __expf(l1-m);
    float sc0 = __fdividef(e0, e0+e1);
    sc[b*(5*T_) + s*T_ + t] = sc0;
    pred[(size_t)b*(L_*5*T_) + (size_t)layer*(5*T_) + s*T_ + t] = sc0;
}

// ---------------- image fusion (both slots, in-place) ----------------
__global__ void img_fuse_kernel(float* __restrict__ X, const float* __restrict__ sc){
    size_t i = (size_t)blockIdx.x*256 + threadIdx.x;
    if (i >= (size_t)BT_*64) return;
    int row = (int)(i>>6), d4 = (int)(i&63);
    int b = row / T_, t = row % T_;
    float s0 = sc[b*(5*T_) + t];
    float s1 = sc[b*(5*T_) + T_ + t];
    float fm0  = (s0 > THRESH)? 1.f : 0.f;
    float fnm0 = -fm0 - 1.f;
    float fm1  = (s1 > THRESH)? 1.f : 0.f;
    float fnm1 = -fm1 - 1.f;
    float4* p0 = ((float4*)(X + (size_t)row*D_)) + d4;
    float4* p1 = ((float4*)(X + ((size_t)BT_ + row)*D_)) + d4;
    float4 a0 = *p0, a1 = *p1;
    float4 r0, r1;
    r0.x = a0.x*fm0 + a1.x*fnm0;  r0.y = a0.y*fm0 + a1.y*fnm0;
    r0.z = a0.z*fm0 + a1.z*fnm0;  r0.w = a0.w*fm0 + a1.w*fnm0;
    r1.x = a1.x*fm1 + a0.x*fnm1;  r1.y = a1.y*fm1 + a0.y*fnm1;
    r1.z = a1.z*fm1 + a0.z*fnm1;  r1.w = a1.w*fm1 + a0.w*fnm1;
    *p0 = r0; *p1 = r1;
}

// ---------------- point fusion: gather TWO rows of PM (MLP outputs) + fuse ----------------
__global__ void pt_fuse_gather_kernel(float* __restrict__ X, const us* __restrict__ PM,
                                      const int* __restrict__ idx, const float* __restrict__ sc){
    size_t i = (size_t)blockIdx.x*256 + threadIdx.x;
    if (i >= (size_t)3*BT_*64) return;
    int vrow = (int)(i>>6), d4 = (int)(i&63);
    int k2 = vrow / BT_, grow = vrow % BT_;
    int b = grow / T_, t = grow % T_;
    float s = sc[b*(5*T_) + (2+k2)*T_ + t];
    float fm  = (s > THRESH)? 1.f : 0.f;
    float fnm = -fm - 1.f;
    int i0 = idx[(size_t)(k2*2+0)*BT_ + grow];
    int i1 = idx[(size_t)(k2*2+1)*BT_ + grow];
    uint2 u0 = ((const uint2*)(PM + ((size_t)b*T_ + i0)*D_))[d4];
    uint2 u1 = ((const uint2*)(PM + ((size_t)BT_ + (size_t)b*T_ + i1)*D_))[d4];
    float p0 = bf2f((us)(u0.x&0xffff)) + bf2f((us)(u1.x&0xffff));
    float p1 = bf2f((us)(u0.x>>16))    + bf2f((us)(u1.x>>16));
    float p2 = bf2f((us)(u0.y&0xffff)) + bf2f((us)(u1.y&0xffff));
    float p3 = bf2f((us)(u0.y>>16))    + bf2f((us)(u1.y>>16));
    float4* xp = ((float4*)(X + ((size_t)(2+k2)*BT_ + grow)*D_)) + d4;
    float4 a = *xp;
    float4 rr;
    rr.x = a.x*fm + p0*fnm;
    rr.y = a.y*fm + p1*fnm;
    rr.z = a.z*fm + p2*fnm;
    rr.w = a.w*fm + p3*fnm;
    *xp = rr;
}

// ---------------- max-pool over 245 tokens (float4 per thread) ----------------
__global__ void pool_kernel(const float* __restrict__ x, float* __restrict__ p){
    int i = blockIdx.x*256 + threadIdx.x;
    if (i >= B_*64) return;
    int b = i>>6, d4 = i&63;
    float4 m; m.x=m.y=m.z=m.w=-3.4e38f;
    for (int s=0;s<5;s++){
        const float4* bp = ((const float4*)(x + ((size_t)s*BT_ + (size_t)b*T_)*D_)) + d4;
        for (int t=0;t<T_;t++){
            float4 v = bp[(size_t)t*64];
            m.x=fmaxf(m.x,v.x); m.y=fmaxf(m.y,v.y); m.z=fmaxf(m.z,v.z); m.w=fmaxf(m.w,v.w);
        }
    }
    ((float4*)p)[i] = m;
}

static inline int cdiv(int a, int b){ return (a+b-1)/b; }

extern "C" void kernel_launch(void* const* d_in, const int* in_sizes, int n_in,
                              void* d_out, int out_size, void* d_ws, size_t ws_size,
                              hipStream_t stream)
{
    const float* in_img0 = (const float*)d_in[0];
    const float* in_img1 = (const float*)d_in[1];
    const float* in_p0   = (const float*)d_in[2];
    const float* in_p1   = (const float*)d_in[3];
    const float* in_p2   = (const float*)d_in[4];
    const int*   in_idx  = (const int*)d_in[5];
    const float* enc_ln1g = (const float*)d_in[6];
    const float* enc_ln1b = (const float*)d_in[7];
    const float* enc_wqkv = (const float*)d_in[8];
    const float* enc_wo   = (const float*)d_in[9];
    const float* enc_bo   = (const float*)d_in[10];
    const float* enc_ln2g = (const float*)d_in[11];
    const float* enc_ln2b = (const float*)d_in[12];
    const float* enc_w1   = (const float*)d_in[13];
    const float* enc_b1   = (const float*)d_in[14];
    const float* enc_w2   = (const float*)d_in[15];
    const float* enc_b2   = (const float*)d_in[16];
    const float* sc_lng   = (const float*)d_in[17];
    const float* sc_lnb   = (const float*)d_in[18];
    const float* sc_w1    = (const float*)d_in[19];
    const float* sc_b1    = (const float*)d_in[20];
    const float* sc_w2    = (const float*)d_in[21];
    const float* sc_b2    = (const float*)d_in[22];
    const float* sc_w3    = (const float*)d_in[23];
    const float* sc_b3    = (const float*)d_in[24];
    const float* pm_w1    = (const float*)d_in[25];
    const float* pm_b1    = (const float*)d_in[26];
    const float* pm_w2    = (const float*)d_in[27];
    const float* pm_b2    = (const float*)d_in[28];
    const float* pm_w3    = (const float*)d_in[29];
    const float* pm_b3    = (const float*)d_in[30];
    const float* hd_lng   = (const float*)d_in[31];
    const float* hd_lnb   = (const float*)d_in[32];
    const float* hd_w1    = (const float*)d_in[33];
    const float* hd_b1    = (const float*)d_in[34];
    const float* hd_w2    = (const float*)d_in[35];
    const float* hd_b2    = (const float*)d_in[36];

    // ---------------- workspace layout ----------------
    char* p = (char*)d_ws;
    float* X   = (float*)p;  p += (size_t)5*BT_*D_*4;
    float* SCb = (float*)p;  p += (size_t)B_*5*T_*4;
    us* PM   = (us*)p; p += (size_t)2*BT_*D_*2;
    us* WQKV = (us*)p; p += (size_t)8*768*256*2;
    us* WWO  = (us*)p; p += (size_t)8*256*256*2;
    us* WW1  = (us*)p; p += (size_t)8*1024*256*2;
    us* WW2  = (us*)p; p += (size_t)8*256*1024*2;
    us* WS1  = (us*)p; p += (size_t)4*256*256*2;
    us* WS2  = (us*)p; p += (size_t)4*128*256*2;
    us* WP1  = (us*)p; p += (size_t)4*1024*256*2;
    us* WP2  = (us*)p; p += (size_t)4*1024*1024*2;
    us* WP3  = (us*)p; p += (size_t)4*256*1024*2;
    us* WH1  = (us*)p; p += (size_t)1024*256*2;
    us* WH2  = (us*)p; p += (size_t)256*1024*2;
    float* B2P  = (float*)p; p += (size_t)256*4;
    float* POOL = (float*)p; p += (size_t)B_*256*4;
    us*    HLNb = (us*)p;  p += (size_t)B_*256*2;
    us*    HMIDb= (us*)p;  p += (size_t)B_*1024*2;
    float* HOUT = (float*)p; p += (size_t)B_*256*4;
    size_t fixed = (size_t)(p - (char*)d_ws);
    long long poolb = (long long)ws_size - (long long)fixed;
    if (poolb < 0) poolb = 0;
    // per-row scratch: encoder 2560 (eR3 aliases eR1), score 1024 (sS2 aliases sR1),
    // patch 4096 (cA aliases m2)
    auto chunkOf = [&](long long perRow, int maxRows)->int{
        long long c = poolb / perRow;
        c = (c / T_) * T_;
        if (c < T_) c = T_;
        if (c > maxRows) c = maxRows;
        return (int)c;
    };
    auto evenC = [&](int total, int Cmax)->int{
        int nch = (total + Cmax - 1)/Cmax;
        int per = (total + nch - 1)/nch;
        per = ((per + T_ - 1)/T_)*T_;
        if (per > Cmax) per = Cmax;
        return per;
    };
    int CencMax = chunkOf(2560, 3*BT_);
    int CscMax  = chunkOf(1024, NTOK5);
    int CpmMax  = chunkOf(4096, 2*BT_);
    char* pb = p;
    us* eR1 = (us*)pb;                                    // [Cenc,256]; eR3 aliases
    us* eR2 = (us*)(pb + (size_t)CencMax*512);            // [Cenc,1024]
    us* eR3 = eR1;
    us* sR1 = (us*)pb;                                    // [Csc,256]; sS2 aliases
    us* sS1 = (us*)(pb + (size_t)CscMax*512);             // [Csc,256]
    us* sS2 = sR1;
    us* m1  = (us*)pb;                                    // [Cpm,1024]
    us* m2  = (us*)(pb + (size_t)CpmMax*2048);            // [Cpm,1024]; cA aliases
    us* cA  = m2;

    float* out_smplx = (float*)d_out;
    float* out_pred  = out_smplx + (size_t)B_*OUT_;

    // ---------------- weight transpose + bf16 convert ----------------
    wtrans_kernel<<<dim3(cdiv(768,32), cdiv(256,32), 8),256,0,stream>>>(enc_wqkv, WQKV, 256, 768);
    wtrans_kernel<<<dim3(cdiv(256,32), cdiv(256,32), 8),256,0,stream>>>(enc_wo,   WWO,  256, 256);
    wtrans_kernel<<<dim3(cdiv(1024,32),cdiv(256,32), 8),256,0,stream>>>(enc_w1,   WW1,  256, 1024);
    wtrans_kernel<<<dim3(cdiv(256,32), cdiv(1024,32),8),256,0,stream>>>(enc_w2,   WW2,  1024,256);
    wtrans_kernel<<<dim3(cdiv(256,32), cdiv(256,32), 4),256,0,stream>>>(sc_w1,    WS1,  256, 256);
    wtrans_kernel<<<dim3(cdiv(128,32), cdiv(256,32), 4),256,0,stream>>>(sc_w2,    WS2,  256, 128);
    wtrans_kernel<<<dim3(cdiv(1024,32),cdiv(256,32), 4),256,0,stream>>>(pm_w1,    WP1,  256, 1024);
    wtrans_kernel<<<dim3(cdiv(1024,32),cdiv(1024,32),4),256,0,stream>>>(pm_w2,    WP2,  1024,1024);
    wtrans_kernel<<<dim3(cdiv(256,32), cdiv(1024,32),4),256,0,stream>>>(pm_w3,    WP3,  1024,256);
    wtrans_kernel<<<dim3(cdiv(1024,32),cdiv(256,32), 1),256,0,stream>>>(hd_w1,    WH1,  256, 1024);
    wtrans_pad_kernel<<<dim3(cdiv(256,32), cdiv(1024,32)),256,0,stream>>>(hd_w2, WH2, 1024, 151, 256);
    padb_kernel<<<1,256,0,stream>>>(hd_b2, B2P, 151, 256);

    copy_in_kernel<<<cdiv(NTOK5*64,256), 256, 0, stream>>>(in_img0,in_img1,in_p0,in_p1,in_p2, X);

    for (int i=0;i<L_;i++){
        // ---------- encoders ----------
        for (int grp=0; grp<2; grp++){
            int base  = (grp==0)? 0 : 2*BT_;
            int total = (grp==0)? 2*BT_ : 3*BT_;
            size_t wi = (size_t)(grp*L_ + i);
            int C = evenC(total, CencMax);
            for (int off=0; off<total; off+=C){
                int R = total-off < C ? total-off : C;
                float* Xp = X + (size_t)(base+off)*D_;
                ln_kernel<true><<<cdiv(R,4),256,0,stream>>>(Xp, enc_ln1g+wi*D_, enc_ln1b+wi*D_, eR1, R);
                mfma_gemm<0,0,true><<<dim3(6, cdiv(R,128)),256,0,stream>>>(
                    eR1, WQKV + wi*768*256, nullptr, nullptr, eR2, R, 768, 256);
                attn_kernel<<<(R/T_)*4,128,0,stream>>>(eR2, eR3);
                mfma_gemm<0,1,false><<<dim3(2, cdiv(R,128)),256,0,stream>>>(
                    eR3, WWO + wi*256*256, enc_bo + wi*D_, Xp, Xp, R, 256, 256);
                ln_kernel<true><<<cdiv(R,4),256,0,stream>>>(Xp, enc_ln2g+wi*D_, enc_ln2b+wi*D_, eR1, R);
                mfma_gemm<1,0,true><<<dim3(8, cdiv(R,128)),256,0,stream>>>(
                    eR1, WW1 + wi*1024*256, enc_b1 + wi*M_, nullptr, eR2, R, 1024, 256);
                mfma_gemm<0,1,false><<<dim3(2, cdiv(R,128)),256,0,stream>>>(
                    eR2, WW2 + wi*256*1024, enc_b2 + wi*D_, Xp, Xp, R, 256, 1024);
            }
        }
        // ---------- score net ----------
        {
            int C = evenC(NTOK5, CscMax);
            for (int off=0; off<NTOK5; off+=C){
                int R = NTOK5-off < C ? NTOK5-off : C;
                ln_kernel<true><<<cdiv(R,4),256,0,stream>>>(X + (size_t)off*D_,
                    sc_lng+(size_t)i*D_, sc_lnb+(size_t)i*D_, sR1, R);
                mfma_gemm<1,0,true><<<dim3(2, cdiv(R,128)),256,0,stream>>>(
                    sR1, WS1 + (size_t)i*256*256, sc_b1+(size_t)i*D_, nullptr, sS1, R, 256, 256);
                mfma_gemm<1,0,true><<<dim3(1, cdiv(R,128)),256,0,stream>>>(
                    sS1, WS2 + (size_t)i*128*256, sc_b2+(size_t)i*128, nullptr, sS2, R, 128, 256);
                score_kernel<<<cdiv(R,256),256,0,stream>>>(
                    sS2, sc_w3+(size_t)i*256, sc_b3+(size_t)i*2, SCb, out_pred, i, off, R);
            }
        }
        // ---------- patch MLP on 2BT image rows (MLP∘gather = gather∘MLP) ----------
        {
            int C = evenC(2*BT_, CpmMax);
            for (int off=0; off<2*BT_; off+=C){
                int R = 2*BT_-off < C ? 2*BT_-off : C;
                xcvt_kernel<<<cdiv(R*64,256),256,0,stream>>>(X + (size_t)off*D_, cA, R);
                mfma_gemm<1,0,true><<<dim3(8, cdiv(R,128)),256,0,stream>>>(
                    cA, WP1 + (size_t)i*1024*256, pm_b1+(size_t)i*M_, nullptr, m1, R, 1024, 256);
                mfma_gemm<1,0,true><<<dim3(8, cdiv(R,128)),256,0,stream>>>(
                    m1, WP2 + (size_t)i*1024*1024, pm_b2+(size_t)i*M_, nullptr, m2, R, 1024, 1024);
                mfma_gemm<0,0,true><<<dim3(2, cdiv(R,128)),256,0,stream>>>(
                    m2, WP3 + (size_t)i*256*1024, pm_b3+(size_t)i*D_, nullptr, PM + (size_t)off*D_, R, 256, 1024);
            }
        }
        pt_fuse_gather_kernel<<<cdiv(3*BT_*64,256),256,0,stream>>>(X, PM, in_idx, SCb);
        img_fuse_kernel<<<cdiv(BT_*64,256),256,0,stream>>>(X, SCb);
    }
    // ---------- head (MFMA path) ----------
    pool_kernel<<<cdiv(B_*64,256),256,0,stream>>>(X, POOL);
    ln_kernel<true><<<cdiv(B_,4),256,0,stream>>>(POOL, hd_lng, hd_lnb, HLNb, B_);
    mfma_gemm<1,0,true><<<dim3(8, cdiv(B_,128)),256,0,stream>>>(
        HLNb, WH1, hd_b1, nullptr, HMIDb, B_, 1024, 256);
    mfma_gemm<0,0,false><<<dim3(2, cdiv(B_,128)),256,0,stream>>>(
        HMIDb, WH2, B2P, nullptr, HOUT, B_, 256, 1024);
    headcopy_kernel<<<cdiv(B_*OUT_,256),256,0,stream>>>(HOUT, out_smplx);
}